// Round 4
// baseline (771.367 us; speedup 1.0000x reference)
//
#include <hip/hip_runtime.h>

// ---------------------------------------------------------------------------
// SiameseTripletModel: out = concat(anchor, pos, pos[argmin_j dist(i,j)])
//   anchor = anchor_x @ W + b ; pos = pos_x @ W + b
//   dist[i,j] = |a_i|^2 + |p_j|^2 - 2 a_i.p_j, diagonal excluded, first-min.
//
// ROUND-4 ROOT CAUSE of rounds 1-3 aborts: I/O is FP32 (per reference dtypes;
// round-0 threshold == exactly 2%*max|ref| proves no bf16 floor was applied).
// Reading fp32 as bf16 produced NaN garbage -> `if (d < best)` never fired ->
// argmin index stayed at sentinel 0x7fffffff -> wild OOB gather -> HSA abort.
//
// This round: fp32 everywhere, vector-ALU GEMMs (no MFMA), d_ws NEVER touched
// (p2 + argmin partials live in out's neg-third, dead until the final gather),
// and the gather index is clamped so no value can ever fault.
// ---------------------------------------------------------------------------

#define B  4096
#define D  1024
#define OLD 3072   // out leading dim (floats)
#define LDK 68     // padded LDS row (floats): 64 + 4, 16B-aligned rows

// ---------------- encoder GEMM: out[:, off:off+1024] = X @ W + b -------------
// NN-form vector GEMM: 64x64 tile, BK=32, 256 threads, 4x4 per thread.
__global__ __launch_bounds__(256) void enc_gemm(
    const float* __restrict__ X,   // [4096,1024]
    const float* __restrict__ W,   // [1024,1024] row-major
    const float* __restrict__ bia, // [1024]
    float* __restrict__ out,       // [4096,3072]
    int outOff) {
  __shared__ float lA[32][LDK];    // [k][m]
  __shared__ float lW[32][LDK];    // [k][n]
  const int tid = threadIdx.x;
  const int Mbase = blockIdx.y * 64;   // 64 blocks
  const int Nbase = blockIdx.x * 64;   // 16 blocks
  const int ty = tid >> 4, tx = tid & 15;
  float acc[4][4] = {};

  for (int k0 = 0; k0 < D; k0 += 32) {
    __syncthreads();
#pragma unroll
    for (int h = 0; h < 2; ++h) {
      const int ch = tid + h * 256;                 // 512 float4 chunks each
      const int r = ch >> 3, c4 = (ch & 7) * 4;     // A: 64 rows x 32 k
      const float4 a4 = *(const float4*)&X[(size_t)(Mbase + r) * D + k0 + c4];
      lA[c4 + 0][r] = a4.x; lA[c4 + 1][r] = a4.y;
      lA[c4 + 2][r] = a4.z; lA[c4 + 3][r] = a4.w;
      const int kr = ch >> 4, nc = (ch & 15) * 4;   // W: 32 k x 64 n (coalesced)
      *(float4*)&lW[kr][nc] = *(const float4*)&W[(size_t)(k0 + kr) * D + Nbase + nc];
    }
    __syncthreads();
#pragma unroll
    for (int kk = 0; kk < 32; ++kk) {
      const float4 av = *(const float4*)&lA[kk][ty * 4];
      const float4 wv = *(const float4*)&lW[kk][tx * 4];
      acc[0][0] += av.x * wv.x; acc[0][1] += av.x * wv.y; acc[0][2] += av.x * wv.z; acc[0][3] += av.x * wv.w;
      acc[1][0] += av.y * wv.x; acc[1][1] += av.y * wv.y; acc[1][2] += av.y * wv.z; acc[1][3] += av.y * wv.w;
      acc[2][0] += av.z * wv.x; acc[2][1] += av.z * wv.y; acc[2][2] += av.z * wv.z; acc[2][3] += av.z * wv.w;
      acc[3][0] += av.w * wv.x; acc[3][1] += av.w * wv.y; acc[3][2] += av.w * wv.z; acc[3][3] += av.w * wv.w;
    }
  }
  const float4 b4 = *(const float4*)&bia[Nbase + tx * 4];
#pragma unroll
  for (int i = 0; i < 4; ++i) {
    const int row = Mbase + ty * 4 + i;
    float4 o;
    o.x = acc[i][0] + b4.x; o.y = acc[i][1] + b4.y;
    o.z = acc[i][2] + b4.z; o.w = acc[i][3] + b4.w;
    *(float4*)&out[(size_t)row * OLD + outOff + Nbase + tx * 4] = o;
  }
}

// ---------------- pos row norms -> out[row*3072 + 2048] ----------------------
__global__ __launch_bounds__(256) void pnorm(float* __restrict__ o) {
  const int row = blockIdx.x, t = threadIdx.x;
  const float4 v = *(const float4*)&o[(size_t)row * OLD + D + t * 4];
  float s = v.x * v.x + v.y * v.y + v.z * v.z + v.w * v.w;
#pragma unroll
  for (int off = 32; off; off >>= 1) s += __shfl_down(s, off, 64);
  __shared__ float wsum[4];
  if ((t & 63) == 0) wsum[t >> 6] = s;
  __syncthreads();
  if (t == 0) o[(size_t)row * OLD + 2048] = wsum[0] + wsum[1] + wsum[2] + wsum[3];
}

// --------- distance GEMM (fp32 vector) + fused per-row argmin ----------------
// anchor = out[:,0:1024], pos = out[:,1024:2048], p2 = out[:,2048].
// Per 64x64 block: per-row (min,idx) partial -> float2 at out[row*3072+2056+2*bx].
__global__ __launch_bounds__(256) void dist_argmin(float* __restrict__ o) {
  __shared__ float lA[32][LDK];
  __shared__ float lB[32][LDK];
  const int tid = threadIdx.x;
  const int Mbase = blockIdx.y * 64, Nbase = blockIdx.x * 64;
  const int ty = tid >> 4, tx = tid & 15;
  float acc[4][4] = {};

  for (int k0 = 0; k0 < D; k0 += 32) {
    __syncthreads();
#pragma unroll
    for (int h = 0; h < 2; ++h) {
      const int ch = tid + h * 256;
      const int r = ch >> 3, c4 = (ch & 7) * 4;
      const float4 a4 = *(const float4*)&o[(size_t)(Mbase + r) * OLD + k0 + c4];
      const float4 b4 = *(const float4*)&o[(size_t)(Nbase + r) * OLD + D + k0 + c4];
      lA[c4 + 0][r] = a4.x; lA[c4 + 1][r] = a4.y;
      lA[c4 + 2][r] = a4.z; lA[c4 + 3][r] = a4.w;
      lB[c4 + 0][r] = b4.x; lB[c4 + 1][r] = b4.y;
      lB[c4 + 2][r] = b4.z; lB[c4 + 3][r] = b4.w;
    }
    __syncthreads();
#pragma unroll
    for (int kk = 0; kk < 32; ++kk) {
      const float4 av = *(const float4*)&lA[kk][ty * 4];
      const float4 bv = *(const float4*)&lB[kk][tx * 4];
      acc[0][0] += av.x * bv.x; acc[0][1] += av.x * bv.y; acc[0][2] += av.x * bv.z; acc[0][3] += av.x * bv.w;
      acc[1][0] += av.y * bv.x; acc[1][1] += av.y * bv.y; acc[1][2] += av.y * bv.z; acc[1][3] += av.y * bv.w;
      acc[2][0] += av.z * bv.x; acc[2][1] += av.z * bv.y; acc[2][2] += av.z * bv.z; acc[2][3] += av.z * bv.w;
      acc[3][0] += av.w * bv.x; acc[3][1] += av.w * bv.y; acc[3][2] += av.w * bv.z; acc[3][3] += av.w * bv.w;
    }
  }

  // d = p2[col] - 2*S (a2[i] is row-constant: argmin-invariant, dropped)
  float colp2[4];
#pragma unroll
  for (int j = 0; j < 4; ++j)
    colp2[j] = o[(size_t)(Nbase + tx * 4 + j) * OLD + 2048];
#pragma unroll
  for (int i = 0; i < 4; ++i) {
    const int rg = Mbase + ty * 4 + i;
    float bv = 3.0e38f; int bj = 0;  // always replaced: >=3 of 4 cols valid
#pragma unroll
    for (int j = 0; j < 4; ++j) {
      const int cg = Nbase + tx * 4 + j;
      const float d = colp2[j] - 2.0f * acc[i][j];
      if (cg != rg && d < bv) { bv = d; bj = cg; }  // j ascends: first-min kept
    }
#pragma unroll
    for (int m = 1; m < 16; m <<= 1) {  // reduce across the 16 tx lanes
      const float ov = __shfl_xor(bv, m, 64);
      const int oj = __shfl_xor(bj, m, 64);
      if (ov < bv || (ov == bv && oj < bj)) { bv = ov; bj = oj; }
    }
    if (tx == 0)
      ((float2*)&o[(size_t)rg * OLD + 2056])[blockIdx.x] =
          make_float2(bv, __int_as_float(bj));
  }
}

// ------------- final: reduce 64 col-block partials, gather neg row -----------
__global__ __launch_bounds__(256) void argmin_final(float* __restrict__ o) {
  const int i = blockIdx.x, t = threadIdx.x;
  __shared__ int sj;
  if (t < 64) {
    const float2 p = ((const float2*)&o[(size_t)i * OLD + 2056])[t];
    float v = p.x;
    int j = __float_as_int(p.y);
#pragma unroll
    for (int m = 32; m; m >>= 1) {
      const float ov = __shfl_xor(v, m, 64);
      const int oj = __shfl_xor(j, m, 64);
      if (ov < v || (ov == v && oj < j)) { v = ov; j = oj; }
    }
    if (t == 0) sj = (j < 0) ? 0 : (j > B - 1 ? B - 1 : j);  // clamp: never fault
  }
  __syncthreads();
  const int j = sj;  // copy pos row j (1024 f32) into neg slot of row i
  ((float4*)&o[(size_t)i * OLD + 2048])[t] = ((const float4*)&o[(size_t)j * OLD + D])[t];
}

extern "C" void kernel_launch(void* const* d_in, const int* in_sizes, int n_in,
                              void* d_out, int out_size, void* d_ws, size_t ws_size,
                              hipStream_t stream) {
  const float* anchor_x = (const float*)d_in[0];  // [4096,1024] f32
  const float* pos_x    = (const float*)d_in[1];  // [4096,1024] f32
  const float* W        = (const float*)d_in[2];  // [1024,1024] f32
  const float* b        = (const float*)d_in[3];  // [1024] f32
  float* out = (float*)d_out;                     // [4096,3072] f32
  (void)d_ws; (void)ws_size;                      // d_ws intentionally unused

  enc_gemm<<<dim3(16, 64), 256, 0, stream>>>(anchor_x, W, b, out, 0);
  enc_gemm<<<dim3(16, 64), 256, 0, stream>>>(pos_x,    W, b, out, 1024);
  pnorm<<<B, 256, 0, stream>>>(out);
  dist_argmin<<<dim3(64, 64), 256, 0, stream>>>(out);
  argmin_final<<<B, 256, 0, stream>>>(out);
}

// Round 5
// 411.529 us; speedup vs baseline: 1.8744x; 1.8744x over previous
//
#include <hip/hip_runtime.h>

// ---------------------------------------------------------------------------
// SiameseTripletModel: out = concat(anchor, pos, pos[argmin_j dist(i,j)])
//   anchor = anchor_x @ W + b ; pos = pos_x @ W + b   (all fp32 I/O)
//   dist[i,j] = |a_i|^2 + |p_j|^2 - 2 a_i.p_j, diagonal excluded, first-min.
//
// Round 5: MFMA everywhere via bf16 multi-split (fp32 has no MFMA on CDNA4).
//   * encoder: x ~ hi+mid (16b), W ~ hi+mid; 3 term-pairs, fp32 MFMA accum.
//   * dist:    activations split hi+mid+lo (24b); 6 term-pairs (hh,hm,mh,
//              hl,lh,mm) -> error at the fp32-accum floor (~1e-4 on dist,
//              the scale at which round 4 passed). All 3 chunks resident in
//              LDS per K-tile -> 96 MFMA : 20 ds_read_b128 per wave-chunk.
//   * argmin fused in dist epilogue; partials+p2 live in out's dead third.
//   * ws needs 52 MB (Aq 24 | Pq 24 | WtQ 4); full round-4 fp32 vector path
//     kept as fallback if ws is smaller (that path passed at 771 us).
// ---------------------------------------------------------------------------

typedef short s8v __attribute__((ext_vector_type(8)));   // 8 bf16 (4 VGPRs)
typedef float f4v __attribute__((ext_vector_type(4)));   // MFMA accumulator
typedef unsigned short u16;

#define B  4096
#define D  1024
#define OLD 3072   // out leading dim (floats)
#define LDK 68     // fallback-path LDS row (floats)

__device__ __forceinline__ u16 f2bf(float f) {
  union { float f; unsigned u; } v; v.f = f;
  unsigned r = v.u + 0x7FFFu + ((v.u >> 16) & 1u);  // RNE
  return (u16)(r >> 16);
}
__device__ __forceinline__ float bf2f(u16 s) {
  union { unsigned u; float f; } v; v.u = ((unsigned)s) << 16;
  return v.f;
}

// ================= W transpose + 2-way split: WtQ[n][hi k | mid k] ===========
__global__ void splitT_W(const float* __restrict__ W, u16* __restrict__ WtQ) {
  __shared__ float tile[32][33];
  const int bx = blockIdx.x * 32, by = blockIdx.y * 32;  // bx: n, by: k
  const int tx = threadIdx.x, ty = threadIdx.y;
  for (int dy = 0; dy < 32; dy += 8)
    tile[ty + dy][tx] = W[(size_t)(by + ty + dy) * D + bx + tx];
  __syncthreads();
  for (int dy = 0; dy < 32; dy += 8) {
    const float v = tile[tx][ty + dy];       // k = by+tx, n = bx+ty+dy
    const u16 h = f2bf(v);
    const size_t o = (size_t)(bx + ty + dy) * 2048 + by + tx;
    WtQ[o] = h;
    WtQ[o + 1024] = f2bf(v - bf2f(h));
  }
}

// ====== encoder MFMA GEMM: out[:,off:off+D] = X @ W + b ; Q = 3-split ========
// A: X fp32 (converted to hi/mid during staging). B: WtQ [n][2048] bf16.
// 3 term-pairs: ah*bh + ah*bm + am*bh. 128x128 tile, BK=32.
__global__ __launch_bounds__(256) void enc_mfma(
    const float* __restrict__ X, const u16* __restrict__ WtQ,
    const float* __restrict__ bias, float* __restrict__ out, int outOff,
    u16* __restrict__ Q) {
  __shared__ __align__(16) u16 lAh[128 * 32], lAm[128 * 32];
  __shared__ __align__(16) u16 lBh[128 * 32], lBm[128 * 32];
  const int tid = threadIdx.x, lane = tid & 63, wave = tid >> 6;
  const int waveM = wave >> 1, waveN = wave & 1;
  const int row16 = lane & 15, quad = lane >> 4;
  const int Mbase = blockIdx.y * 128;   // 32 blocks
  const int Nbase = blockIdx.x * 128;   // 8 blocks
  f4v acc[4][4] = {};

  for (int kk = 0; kk < D; kk += 32) {
    __syncthreads();
    // A: 128x32 fp32 -> split to hi/mid bf16 in LDS. 1024 float4 chunks.
#pragma unroll
    for (int h = 0; h < 4; ++h) {
      const int c = tid + h * 256;
      const int r = c >> 3, c4 = (c & 7) * 4;
      const float4 v = *(const float4*)&X[(size_t)(Mbase + r) * D + kk + c4];
      const float vv[4] = {v.x, v.y, v.z, v.w};
      ushort4 hi, mi;
      u16* hp = &hi.x; u16* mp = &mi.x;
#pragma unroll
      for (int i = 0; i < 4; ++i) {
        hp[i] = f2bf(vv[i]);
        mp[i] = f2bf(vv[i] - bf2f(hp[i]));
      }
      *(ushort4*)&lAh[r * 32 + c4] = hi;
      *(ushort4*)&lAm[r * 32 + c4] = mi;
    }
    // B: WtQ hi and mid, 512 uint4 chunks each.
#pragma unroll
    for (int h = 0; h < 2; ++h) {
      const int c = tid + h * 256;
      const int r = c >> 2, q8 = (c & 3) * 8;
      const size_t g = (size_t)(Nbase + r) * 2048 + kk + q8;
      *(uint4*)&lBh[r * 32 + q8] = *(const uint4*)&WtQ[g];
      *(uint4*)&lBm[r * 32 + q8] = *(const uint4*)&WtQ[g + 1024];
    }
    __syncthreads();
    s8v ah[4], am[4], bh[4], bm[4];
#pragma unroll
    for (int mi = 0; mi < 4; ++mi) {
      const int ro = (waveM * 64 + mi * 16 + row16) * 32 + quad * 8;
      ah[mi] = *(const s8v*)&lAh[ro];
      am[mi] = *(const s8v*)&lAm[ro];
    }
#pragma unroll
    for (int ni = 0; ni < 4; ++ni) {
      const int ro = (waveN * 64 + ni * 16 + row16) * 32 + quad * 8;
      bh[ni] = *(const s8v*)&lBh[ro];
      bm[ni] = *(const s8v*)&lBm[ro];
    }
#pragma unroll
    for (int mi = 0; mi < 4; ++mi)
#pragma unroll
      for (int ni = 0; ni < 4; ++ni) {
        f4v a = acc[mi][ni];
        a = __builtin_amdgcn_mfma_f32_16x16x32_bf16(ah[mi], bh[ni], a, 0, 0, 0);
        a = __builtin_amdgcn_mfma_f32_16x16x32_bf16(ah[mi], bm[ni], a, 0, 0, 0);
        a = __builtin_amdgcn_mfma_f32_16x16x32_bf16(am[mi], bh[ni], a, 0, 0, 0);
        acc[mi][ni] = a;
      }
  }
  // C/D layout: col = lane&15, row = quad*4 + r  [m89/m91 verified]
#pragma unroll
  for (int ni = 0; ni < 4; ++ni) {
    const int col = Nbase + waveN * 64 + ni * 16 + row16;
    const float bv = bias[col];
#pragma unroll
    for (int mi = 0; mi < 4; ++mi) {
      const int rbase = Mbase + waveM * 64 + mi * 16 + quad * 4;
#pragma unroll
      for (int r = 0; r < 4; ++r) {
        const size_t row = rbase + r;
        const float v = acc[mi][ni][r] + bv;
        out[row * OLD + outOff + col] = v;
        const u16 h = f2bf(v);
        const float r1 = v - bf2f(h);
        const u16 m = f2bf(r1);
        Q[row * 3072 + col] = h;
        Q[row * 3072 + 1024 + col] = m;
        Q[row * 3072 + 2048 + col] = f2bf(r1 - bf2f(m));
      }
    }
  }
}

// ---------------- pos row norms -> out[row*3072 + 2048] ----------------------
__global__ __launch_bounds__(256) void pnorm(float* __restrict__ o) {
  const int row = blockIdx.x, t = threadIdx.x;
  const float4 v = *(const float4*)&o[(size_t)row * OLD + D + t * 4];
  float s = v.x * v.x + v.y * v.y + v.z * v.z + v.w * v.w;
#pragma unroll
  for (int off = 32; off; off >>= 1) s += __shfl_down(s, off, 64);
  __shared__ float wsum[4];
  if ((t & 63) == 0) wsum[t >> 6] = s;
  __syncthreads();
  if (t == 0) o[(size_t)row * OLD + 2048] = wsum[0] + wsum[1] + wsum[2] + wsum[3];
}

// ====== dist MFMA GEMM (6 split pairs, K_eff=6144) + fused argmin ============
// Aq/Pq: [4096][hi|mid|lo] bf16, ld 3072. All 3 chunks of a 32-K tile resident.
__global__ __launch_bounds__(256) void dist_mfma(
    const u16* __restrict__ Aq, const u16* __restrict__ Pq, float* __restrict__ o) {
  __shared__ __align__(16) u16 lA[3][128 * 32];
  __shared__ __align__(16) u16 lB[3][128 * 32];
  __shared__ float sval[128][2];
  __shared__ int sidx[128][2];
  const int tid = threadIdx.x, lane = tid & 63, wave = tid >> 6;
  const int waveM = wave >> 1, waveN = wave & 1;
  const int row16 = lane & 15, quad = lane >> 4;
  const int Mbase = blockIdx.y * 128;
  const int Nbase = blockIdx.x * 128;
  f4v acc[4][4] = {};
  const int r0 = tid >> 2, q0 = (tid & 3) * 8;          // chunk tid
  const int r1 = (tid + 256) >> 2, q1 = ((tid + 256) & 3) * 8;

  for (int kk = 0; kk < D; kk += 32) {
    __syncthreads();
#pragma unroll
    for (int s = 0; s < 3; ++s) {
      const size_t off = (size_t)s * 1024 + kk;
      *(uint4*)&lA[s][r0 * 32 + q0] = *(const uint4*)&Aq[(size_t)(Mbase + r0) * 3072 + off + q0];
      *(uint4*)&lA[s][r1 * 32 + q1] = *(const uint4*)&Aq[(size_t)(Mbase + r1) * 3072 + off + q1];
      *(uint4*)&lB[s][r0 * 32 + q0] = *(const uint4*)&Pq[(size_t)(Nbase + r0) * 3072 + off + q0];
      *(uint4*)&lB[s][r1 * 32 + q1] = *(const uint4*)&Pq[(size_t)(Nbase + r1) * 3072 + off + q1];
    }
    __syncthreads();
    int aro[4], bro[4];
#pragma unroll
    for (int i = 0; i < 4; ++i) {
      aro[i] = (waveM * 64 + i * 16 + row16) * 32 + quad * 8;
      bro[i] = (waveN * 64 + i * 16 + row16) * 32 + quad * 8;
    }
    s8v ah[4], a2[4], bh[4], b2[4];
#pragma unroll
    for (int i = 0; i < 4; ++i) { ah[i] = *(const s8v*)&lA[0][aro[i]]; bh[i] = *(const s8v*)&lB[0][bro[i]]; }
#pragma unroll
    for (int mi = 0; mi < 4; ++mi)
#pragma unroll
      for (int ni = 0; ni < 4; ++ni)   // hi*hi
        acc[mi][ni] = __builtin_amdgcn_mfma_f32_16x16x32_bf16(ah[mi], bh[ni], acc[mi][ni], 0, 0, 0);
#pragma unroll
    for (int i = 0; i < 4; ++i) { a2[i] = *(const s8v*)&lA[1][aro[i]]; b2[i] = *(const s8v*)&lB[1][bro[i]]; }
#pragma unroll
    for (int mi = 0; mi < 4; ++mi)
#pragma unroll
      for (int ni = 0; ni < 4; ++ni) { // mid*hi, hi*mid, mid*mid
        f4v a = acc[mi][ni];
        a = __builtin_amdgcn_mfma_f32_16x16x32_bf16(a2[mi], bh[ni], a, 0, 0, 0);
        a = __builtin_amdgcn_mfma_f32_16x16x32_bf16(ah[mi], b2[ni], a, 0, 0, 0);
        a = __builtin_amdgcn_mfma_f32_16x16x32_bf16(a2[mi], b2[ni], a, 0, 0, 0);
        acc[mi][ni] = a;
      }
#pragma unroll
    for (int i = 0; i < 4; ++i) { a2[i] = *(const s8v*)&lA[2][aro[i]]; b2[i] = *(const s8v*)&lB[2][bro[i]]; }
#pragma unroll
    for (int mi = 0; mi < 4; ++mi)
#pragma unroll
      for (int ni = 0; ni < 4; ++ni) { // lo*hi, hi*lo
        f4v a = acc[mi][ni];
        a = __builtin_amdgcn_mfma_f32_16x16x32_bf16(a2[mi], bh[ni], a, 0, 0, 0);
        a = __builtin_amdgcn_mfma_f32_16x16x32_bf16(ah[mi], b2[ni], a, 0, 0, 0);
        acc[mi][ni] = a;
      }
  }

  // fused argmin epilogue: d = p2[col] - 2*S (a2[i] row-constant, dropped).
  float p2c[4];
#pragma unroll
  for (int ni = 0; ni < 4; ++ni)
    p2c[ni] = o[(size_t)(Nbase + waveN * 64 + ni * 16 + row16) * OLD + 2048];
  float bv[16]; int bj[16];
#pragma unroll
  for (int mi = 0; mi < 4; ++mi)
#pragma unroll
    for (int r = 0; r < 4; ++r) {
      const int e = mi * 4 + r;
      const int rg = Mbase + waveM * 64 + mi * 16 + quad * 4 + r;
      float best = 3.0e38f; int bidx = 0;  // >=3 of 4 cols valid -> always set
#pragma unroll
      for (int ni = 0; ni < 4; ++ni) {
        const int cg = Nbase + waveN * 64 + ni * 16 + row16;
        const float d = p2c[ni] - 2.0f * acc[mi][ni][r];
        if (cg != rg && d < best) { best = d; bidx = cg; }  // ni ascends: first-min
      }
      bv[e] = best; bj[e] = bidx;
    }
#pragma unroll
  for (int m = 1; m < 16; m <<= 1) {  // reduce across the 16 row16 lanes
#pragma unroll
    for (int e = 0; e < 16; ++e) {
      const float ov = __shfl_xor(bv[e], m, 64);
      const int oj = __shfl_xor(bj[e], m, 64);
      if (ov < bv[e] || (ov == bv[e] && oj < bj[e])) { bv[e] = ov; bj[e] = oj; }
    }
  }
  if (row16 == 0) {
#pragma unroll
    for (int e = 0; e < 16; ++e) {
      const int rl = waveM * 64 + (e >> 2) * 16 + quad * 4 + (e & 3);
      sval[rl][waveN] = bv[e];
      sidx[rl][waveN] = bj[e];
    }
  }
  __syncthreads();
  if (tid < 128) {
    const float v0 = sval[tid][0], v1 = sval[tid][1];
    const int j0 = sidx[tid][0], j1 = sidx[tid][1];
    const bool t1 = (v1 < v0) || (v1 == v0 && j1 < j0);
    ((float2*)&o[(size_t)(Mbase + tid) * OLD + 2056])[blockIdx.x] =
        make_float2(t1 ? v1 : v0, __int_as_float(t1 ? j1 : j0));
  }
}

// ------------- final: reduce col-block partials, gather neg row --------------
__global__ __launch_bounds__(256) void argmin_final(float* __restrict__ o, int nblk) {
  const int i = blockIdx.x, t = threadIdx.x;
  __shared__ int sj;
  if (t < 64) {
    float v = 3.4e38f; int j = 0x7fffffff;
    if (t < nblk) {
      const float2 p = ((const float2*)&o[(size_t)i * OLD + 2056])[t];
      v = p.x; j = __float_as_int(p.y);
    }
#pragma unroll
    for (int m = 32; m; m >>= 1) {
      const float ov = __shfl_xor(v, m, 64);
      const int oj = __shfl_xor(j, m, 64);
      if (ov < v || (ov == v && oj < j)) { v = ov; j = oj; }
    }
    if (t == 0) sj = (j < 0) ? 0 : (j > B - 1 ? B - 1 : j);  // clamp: never fault
  }
  __syncthreads();
  const int j = sj;
  ((float4*)&o[(size_t)i * OLD + 2048])[t] = ((const float4*)&o[(size_t)j * OLD + D])[t];
}

// ================== round-4 fallback path (fp32 vector, ws-free) =============
__global__ __launch_bounds__(256) void enc_gemm(
    const float* __restrict__ X, const float* __restrict__ W,
    const float* __restrict__ bia, float* __restrict__ out, int outOff) {
  __shared__ float lA[32][LDK];
  __shared__ float lW[32][LDK];
  const int tid = threadIdx.x;
  const int Mbase = blockIdx.y * 64;
  const int Nbase = blockIdx.x * 64;
  const int ty = tid >> 4, tx = tid & 15;
  float acc[4][4] = {};
  for (int k0 = 0; k0 < D; k0 += 32) {
    __syncthreads();
#pragma unroll
    for (int h = 0; h < 2; ++h) {
      const int ch = tid + h * 256;
      const int r = ch >> 3, c4 = (ch & 7) * 4;
      const float4 a4 = *(const float4*)&X[(size_t)(Mbase + r) * D + k0 + c4];
      lA[c4 + 0][r] = a4.x; lA[c4 + 1][r] = a4.y;
      lA[c4 + 2][r] = a4.z; lA[c4 + 3][r] = a4.w;
      const int kr = ch >> 4, nc = (ch & 15) * 4;
      *(float4*)&lW[kr][nc] = *(const float4*)&W[(size_t)(k0 + kr) * D + Nbase + nc];
    }
    __syncthreads();
#pragma unroll
    for (int kk = 0; kk < 32; ++kk) {
      const float4 av = *(const float4*)&lA[kk][ty * 4];
      const float4 wv = *(const float4*)&lW[kk][tx * 4];
      acc[0][0] += av.x * wv.x; acc[0][1] += av.x * wv.y; acc[0][2] += av.x * wv.z; acc[0][3] += av.x * wv.w;
      acc[1][0] += av.y * wv.x; acc[1][1] += av.y * wv.y; acc[1][2] += av.y * wv.z; acc[1][3] += av.y * wv.w;
      acc[2][0] += av.z * wv.x; acc[2][1] += av.z * wv.y; acc[2][2] += av.z * wv.z; acc[2][3] += av.z * wv.w;
      acc[3][0] += av.w * wv.x; acc[3][1] += av.w * wv.y; acc[3][2] += av.w * wv.z; acc[3][3] += av.w * wv.w;
    }
  }
  const float4 b4 = *(const float4*)&bia[Nbase + tx * 4];
#pragma unroll
  for (int i = 0; i < 4; ++i) {
    const int row = Mbase + ty * 4 + i;
    float4 ov;
    ov.x = acc[i][0] + b4.x; ov.y = acc[i][1] + b4.y;
    ov.z = acc[i][2] + b4.z; ov.w = acc[i][3] + b4.w;
    *(float4*)&out[(size_t)row * OLD + outOff + Nbase + tx * 4] = ov;
  }
}

__global__ __launch_bounds__(256) void dist_argmin_f32(float* __restrict__ o) {
  __shared__ float lA[32][LDK];
  __shared__ float lB[32][LDK];
  const int tid = threadIdx.x;
  const int Mbase = blockIdx.y * 64, Nbase = blockIdx.x * 64;
  const int ty = tid >> 4, tx = tid & 15;
  float acc[4][4] = {};
  for (int k0 = 0; k0 < D; k0 += 32) {
    __syncthreads();
#pragma unroll
    for (int h = 0; h < 2; ++h) {
      const int ch = tid + h * 256;
      const int r = ch >> 3, c4 = (ch & 7) * 4;
      const float4 a4 = *(const float4*)&o[(size_t)(Mbase + r) * OLD + k0 + c4];
      const float4 b4 = *(const float4*)&o[(size_t)(Nbase + r) * OLD + D + k0 + c4];
      lA[c4 + 0][r] = a4.x; lA[c4 + 1][r] = a4.y;
      lA[c4 + 2][r] = a4.z; lA[c4 + 3][r] = a4.w;
      lB[c4 + 0][r] = b4.x; lB[c4 + 1][r] = b4.y;
      lB[c4 + 2][r] = b4.z; lB[c4 + 3][r] = b4.w;
    }
    __syncthreads();
#pragma unroll
    for (int kk = 0; kk < 32; ++kk) {
      const float4 av = *(const float4*)&lA[kk][ty * 4];
      const float4 bv = *(const float4*)&lB[kk][tx * 4];
      acc[0][0] += av.x * bv.x; acc[0][1] += av.x * bv.y; acc[0][2] += av.x * bv.z; acc[0][3] += av.x * bv.w;
      acc[1][0] += av.y * bv.x; acc[1][1] += av.y * bv.y; acc[1][2] += av.y * bv.z; acc[1][3] += av.y * bv.w;
      acc[2][0] += av.z * bv.x; acc[2][1] += av.z * bv.y; acc[2][2] += av.z * bv.z; acc[2][3] += av.z * bv.w;
      acc[3][0] += av.w * bv.x; acc[3][1] += av.w * bv.y; acc[3][2] += av.w * bv.z; acc[3][3] += av.w * bv.w;
    }
  }
  float colp2[4];
#pragma unroll
  for (int j = 0; j < 4; ++j)
    colp2[j] = o[(size_t)(Nbase + tx * 4 + j) * OLD + 2048];
#pragma unroll
  for (int i = 0; i < 4; ++i) {
    const int rg = Mbase + ty * 4 + i;
    float bv = 3.0e38f; int bj = 0;
#pragma unroll
    for (int j = 0; j < 4; ++j) {
      const int cg = Nbase + tx * 4 + j;
      const float d = colp2[j] - 2.0f * acc[i][j];
      if (cg != rg && d < bv) { bv = d; bj = cg; }
    }
#pragma unroll
    for (int m = 1; m < 16; m <<= 1) {
      const float ov = __shfl_xor(bv, m, 64);
      const int oj = __shfl_xor(bj, m, 64);
      if (ov < bv || (ov == bv && oj < bj)) { bv = ov; bj = oj; }
    }
    if (tx == 0)
      ((float2*)&o[(size_t)rg * OLD + 2056])[blockIdx.x] =
          make_float2(bv, __int_as_float(bj));
  }
}

extern "C" void kernel_launch(void* const* d_in, const int* in_sizes, int n_in,
                              void* d_out, int out_size, void* d_ws, size_t ws_size,
                              hipStream_t stream) {
  const float* anchor_x = (const float*)d_in[0];  // [4096,1024] f32
  const float* pos_x    = (const float*)d_in[1];  // [4096,1024] f32
  const float* W        = (const float*)d_in[2];  // [1024,1024] f32
  const float* b        = (const float*)d_in[3];  // [1024] f32
  float* out = (float*)d_out;                     // [4096,3072] f32
  char* ws = (char*)d_ws;
  const size_t MB = 1024 * 1024;

  if (ws_size >= 52 * MB) {
    u16* Aq  = (u16*)(ws);            // [4096][3072] bf16 hi|mid|lo, 24 MB
    u16* Pq  = (u16*)(ws + 24 * MB);  // 24 MB
    u16* WtQ = (u16*)(ws + 48 * MB);  // [1024][2048] bf16 hi|mid, 4 MB
    splitT_W<<<dim3(32, 32), dim3(32, 8), 0, stream>>>(W, WtQ);
    enc_mfma<<<dim3(8, 32), 256, 0, stream>>>(anchor_x, WtQ, b, out, 0, Aq);
    enc_mfma<<<dim3(8, 32), 256, 0, stream>>>(pos_x,    WtQ, b, out, 1024, Pq);
    pnorm<<<B, 256, 0, stream>>>(out);
    dist_mfma<<<dim3(32, 32), 256, 0, stream>>>(Aq, Pq, out);
    argmin_final<<<B, 256, 0, stream>>>(out, 32);
  } else {  // round-4 proven path: d_ws untouched
    enc_gemm<<<dim3(16, 64), 256, 0, stream>>>(anchor_x, W, b, out, 0);
    enc_gemm<<<dim3(16, 64), 256, 0, stream>>>(pos_x,    W, b, out, 1024);
    pnorm<<<B, 256, 0, stream>>>(out);
    dist_argmin_f32<<<dim3(64, 64), 256, 0, stream>>>(out);
    argmin_final<<<B, 256, 0, stream>>>(out, 64);
  }
}

// Round 6
// 381.585 us; speedup vs baseline: 2.0215x; 1.0785x over previous
//
#include <hip/hip_runtime.h>

// ---------------------------------------------------------------------------
// SiameseTripletModel: out = concat(anchor, pos, pos[argmin_j dist(i,j)])
//   anchor = anchor_x @ W + b ; pos = pos_x @ W + b   (all fp32 I/O)
//   dist[i,j] = |a_i|^2 + |p_j|^2 - 2 a_i.p_j, diagonal excluded, first-min.
//
// Round 6 (on top of round-5 MFMA multi-split, 411 us):
//   * global->LDS staging via __builtin_amdgcn_global_load_lds width=16 in
//     both MFMA GEMMs (async DMA, no VGPR round-trip; LDS dest is exactly
//     wave-uniform base + lane*16B in our chunk layout).
//   * X pre-split to bf16 hi/mid ONCE (splitX) into out's dead neg-third;
//     encoder A-staging becomes pure DMA (was 32 f2bf VALU/thread/iter x8
//     redundant across N-blocks).
//   * dist: 3-way split (hi/mid/lo), 6 MFMA term-pairs -> ~1e-5 dist error.
//   * argmin fused in dist epilogue; p2+partials in out's dead third;
//     final gather index clamped (no fault possible on any garbage).
//   * round-4 fp32 vector path kept as fallback for ws < 52 MB.
// ---------------------------------------------------------------------------

typedef short s8v __attribute__((ext_vector_type(8)));   // 8 bf16 (4 VGPRs)
typedef float f4v __attribute__((ext_vector_type(4)));   // MFMA accumulator
typedef unsigned short u16;

#define B  4096
#define D  1024
#define OLD 3072   // out leading dim (floats)
#define OLD16 6144 // out leading dim (u16)
#define LDK 68     // fallback-path LDS row (floats)

__device__ __forceinline__ u16 f2bf(float f) {
  union { float f; unsigned u; } v; v.f = f;
  unsigned r = v.u + 0x7FFFu + ((v.u >> 16) & 1u);  // RNE
  return (u16)(r >> 16);
}
__device__ __forceinline__ float bf2f(u16 s) {
  union { unsigned u; float f; } v; v.u = ((unsigned)s) << 16;
  return v.f;
}

// async 16B global->LDS (lds dest must be wave-uniform; lane i lands at +16*i)
__device__ __forceinline__ void gld16(const void* g, void* l) {
  __builtin_amdgcn_global_load_lds(
      (const __attribute__((address_space(1))) unsigned int*)g,
      (__attribute__((address_space(3))) unsigned int*)l, 16, 0, 0);
}

// ================= W transpose + 2-way split: WtQ[n][hi k | mid k] ===========
__global__ void splitT_W(const float* __restrict__ W, u16* __restrict__ WtQ) {
  __shared__ float tile[32][33];
  const int bx = blockIdx.x * 32, by = blockIdx.y * 32;  // bx: n, by: k
  const int tx = threadIdx.x, ty = threadIdx.y;
  for (int dy = 0; dy < 32; dy += 8)
    tile[ty + dy][tx] = W[(size_t)(by + ty + dy) * D + bx + tx];
  __syncthreads();
  for (int dy = 0; dy < 32; dy += 8) {
    const float v = tile[tx][ty + dy];       // k = by+tx, n = bx+ty+dy
    const u16 h = f2bf(v);
    const size_t o = (size_t)(bx + ty + dy) * 2048 + by + tx;
    WtQ[o] = h;
    WtQ[o + 1024] = f2bf(v - bf2f(h));
  }
}

// ============ X split to bf16 hi/mid, packed into out's dead third ===========
// O16[r][4096+k] = hi, O16[r][5120+k] = mid  (u16 view of out)
__global__ __launch_bounds__(256) void splitX(const float* __restrict__ X,
                                              u16* __restrict__ O16) {
  const int r = blockIdx.x, t = threadIdx.x;
  const float4 v = *(const float4*)&X[(size_t)r * D + t * 4];
  const float vv[4] = {v.x, v.y, v.z, v.w};
  ushort4 hi, mi;
  u16* hp = &hi.x; u16* mp = &mi.x;
#pragma unroll
  for (int i = 0; i < 4; ++i) {
    hp[i] = f2bf(vv[i]);
    mp[i] = f2bf(vv[i] - bf2f(hp[i]));
  }
  *(ushort4*)&O16[(size_t)r * OLD16 + 4096 + t * 4] = hi;
  *(ushort4*)&O16[(size_t)r * OLD16 + 5120 + t * 4] = mi;
}

// ====== encoder MFMA GEMM: out[:,off:off+D] = X @ W + b ; Q = 3-split ========
// A: Xsplit (hi/mid bf16 in out's dead third). B: WtQ [n][2048] bf16.
// 3 term-pairs: ah*bh + ah*bm + am*bh. 128x128 tile, BK=32. All staging DMA.
__global__ __launch_bounds__(256) void enc_mfma(
    float* out /* aliased: fp32 dst + u16 Xsplit src */,
    const u16* __restrict__ WtQ, const float* __restrict__ bias, int outOff,
    u16* __restrict__ Q) {
  __shared__ __align__(16) u16 lAh[128 * 32], lAm[128 * 32];
  __shared__ __align__(16) u16 lBh[128 * 32], lBm[128 * 32];
  const u16* O16 = (const u16*)out;
  const int tid = threadIdx.x, lane = tid & 63, wave = tid >> 6;
  const int waveM = wave >> 1, waveN = wave & 1;
  const int row16 = lane & 15, quad = lane >> 4;
  const int Mbase = blockIdx.y * 128;   // 32 blocks
  const int Nbase = blockIdx.x * 128;   // 8 blocks
  f4v acc[4][4] = {};

  for (int kk = 0; kk < D; kk += 32) {
    __syncthreads();
#pragma unroll
    for (int i = 0; i < 2; ++i) {
      const int c = i * 256 + wave * 64 + lane;     // 16B chunk id (0..511)
      const int row = c >> 2, col8 = (c & 3) * 8;
      const int lo = (i * 256 + wave * 64) * 8;     // wave-uniform LDS base
      gld16(&O16[(size_t)(Mbase + row) * OLD16 + 4096 + kk + col8], &lAh[lo]);
      gld16(&O16[(size_t)(Mbase + row) * OLD16 + 5120 + kk + col8], &lAm[lo]);
      gld16(&WtQ[(size_t)(Nbase + row) * 2048 + kk + col8], &lBh[lo]);
      gld16(&WtQ[(size_t)(Nbase + row) * 2048 + 1024 + kk + col8], &lBm[lo]);
    }
    __syncthreads();
    s8v ah[4], am[4], bh[4], bm[4];
#pragma unroll
    for (int mi = 0; mi < 4; ++mi) {
      const int ro = (waveM * 64 + mi * 16 + row16) * 32 + quad * 8;
      ah[mi] = *(const s8v*)&lAh[ro];
      am[mi] = *(const s8v*)&lAm[ro];
    }
#pragma unroll
    for (int ni = 0; ni < 4; ++ni) {
      const int ro = (waveN * 64 + ni * 16 + row16) * 32 + quad * 8;
      bh[ni] = *(const s8v*)&lBh[ro];
      bm[ni] = *(const s8v*)&lBm[ro];
    }
#pragma unroll
    for (int mi = 0; mi < 4; ++mi)
#pragma unroll
      for (int ni = 0; ni < 4; ++ni) {
        f4v a = acc[mi][ni];
        a = __builtin_amdgcn_mfma_f32_16x16x32_bf16(ah[mi], bh[ni], a, 0, 0, 0);
        a = __builtin_amdgcn_mfma_f32_16x16x32_bf16(ah[mi], bm[ni], a, 0, 0, 0);
        a = __builtin_amdgcn_mfma_f32_16x16x32_bf16(am[mi], bh[ni], a, 0, 0, 0);
        acc[mi][ni] = a;
      }
  }
  // C/D layout: col = lane&15, row = quad*4 + r  [m89/m91 verified]
#pragma unroll
  for (int ni = 0; ni < 4; ++ni) {
    const int col = Nbase + waveN * 64 + ni * 16 + row16;
    const float bv = bias[col];
#pragma unroll
    for (int mi = 0; mi < 4; ++mi) {
      const int rbase = Mbase + waveM * 64 + mi * 16 + quad * 4;
#pragma unroll
      for (int r = 0; r < 4; ++r) {
        const size_t row = rbase + r;
        const float v = acc[mi][ni][r] + bv;
        out[row * OLD + outOff + col] = v;
        const u16 h = f2bf(v);
        const float r1 = v - bf2f(h);
        const u16 m = f2bf(r1);
        Q[row * 3072 + col] = h;
        Q[row * 3072 + 1024 + col] = m;
        Q[row * 3072 + 2048 + col] = f2bf(r1 - bf2f(m));
      }
    }
  }
}

// ---------------- pos row norms -> out[row*3072 + 2048] ----------------------
__global__ __launch_bounds__(256) void pnorm(float* __restrict__ o) {
  const int row = blockIdx.x, t = threadIdx.x;
  const float4 v = *(const float4*)&o[(size_t)row * OLD + D + t * 4];
  float s = v.x * v.x + v.y * v.y + v.z * v.z + v.w * v.w;
#pragma unroll
  for (int off = 32; off; off >>= 1) s += __shfl_down(s, off, 64);
  __shared__ float wsum[4];
  if ((t & 63) == 0) wsum[t >> 6] = s;
  __syncthreads();
  if (t == 0) o[(size_t)row * OLD + 2048] = wsum[0] + wsum[1] + wsum[2] + wsum[3];
}

// ====== dist MFMA GEMM (6 split pairs, K_eff=6144) + fused argmin ============
// Aq/Pq: [4096][hi|mid|lo] bf16, ld 3072. All staging via async DMA.
__global__ __launch_bounds__(256) void dist_mfma(
    const u16* __restrict__ Aq, const u16* __restrict__ Pq, float* __restrict__ o) {
  __shared__ __align__(16) u16 lA[3][128 * 32];
  __shared__ __align__(16) u16 lB[3][128 * 32];
  __shared__ float sval[128][2];
  __shared__ int sidx[128][2];
  const int tid = threadIdx.x, lane = tid & 63, wave = tid >> 6;
  const int waveM = wave >> 1, waveN = wave & 1;
  const int row16 = lane & 15, quad = lane >> 4;
  const int Mbase = blockIdx.y * 128;
  const int Nbase = blockIdx.x * 128;
  f4v acc[4][4] = {};

  for (int kk = 0; kk < D; kk += 32) {
    __syncthreads();
#pragma unroll
    for (int s = 0; s < 3; ++s) {
#pragma unroll
      for (int i = 0; i < 2; ++i) {
        const int c = i * 256 + wave * 64 + lane;   // 16B chunk id
        const int row = c >> 2, col8 = (c & 3) * 8;
        const int lo = (i * 256 + wave * 64) * 8;   // wave-uniform LDS base
        gld16(&Aq[(size_t)(Mbase + row) * 3072 + s * 1024 + kk + col8], &lA[s][lo]);
        gld16(&Pq[(size_t)(Nbase + row) * 3072 + s * 1024 + kk + col8], &lB[s][lo]);
      }
    }
    __syncthreads();
    int aro[4], bro[4];
#pragma unroll
    for (int i = 0; i < 4; ++i) {
      aro[i] = (waveM * 64 + i * 16 + row16) * 32 + quad * 8;
      bro[i] = (waveN * 64 + i * 16 + row16) * 32 + quad * 8;
    }
    s8v ah[4], a2[4], bh[4], b2[4];
#pragma unroll
    for (int i = 0; i < 4; ++i) { ah[i] = *(const s8v*)&lA[0][aro[i]]; bh[i] = *(const s8v*)&lB[0][bro[i]]; }
#pragma unroll
    for (int mi = 0; mi < 4; ++mi)
#pragma unroll
      for (int ni = 0; ni < 4; ++ni)   // hi*hi
        acc[mi][ni] = __builtin_amdgcn_mfma_f32_16x16x32_bf16(ah[mi], bh[ni], acc[mi][ni], 0, 0, 0);
#pragma unroll
    for (int i = 0; i < 4; ++i) { a2[i] = *(const s8v*)&lA[1][aro[i]]; b2[i] = *(const s8v*)&lB[1][bro[i]]; }
#pragma unroll
    for (int mi = 0; mi < 4; ++mi)
#pragma unroll
      for (int ni = 0; ni < 4; ++ni) { // mid*hi, hi*mid, mid*mid
        f4v a = acc[mi][ni];
        a = __builtin_amdgcn_mfma_f32_16x16x32_bf16(a2[mi], bh[ni], a, 0, 0, 0);
        a = __builtin_amdgcn_mfma_f32_16x16x32_bf16(ah[mi], b2[ni], a, 0, 0, 0);
        a = __builtin_amdgcn_mfma_f32_16x16x32_bf16(a2[mi], b2[ni], a, 0, 0, 0);
        acc[mi][ni] = a;
      }
#pragma unroll
    for (int i = 0; i < 4; ++i) { a2[i] = *(const s8v*)&lA[2][aro[i]]; b2[i] = *(const s8v*)&lB[2][bro[i]]; }
#pragma unroll
    for (int mi = 0; mi < 4; ++mi)
#pragma unroll
      for (int ni = 0; ni < 4; ++ni) { // lo*hi, hi*lo
        f4v a = acc[mi][ni];
        a = __builtin_amdgcn_mfma_f32_16x16x32_bf16(a2[mi], bh[ni], a, 0, 0, 0);
        a = __builtin_amdgcn_mfma_f32_16x16x32_bf16(ah[mi], b2[ni], a, 0, 0, 0);
        acc[mi][ni] = a;
      }
  }

  // fused argmin epilogue: d = p2[col] - 2*S (a2[i] row-constant, dropped).
  float p2c[4];
#pragma unroll
  for (int ni = 0; ni < 4; ++ni)
    p2c[ni] = o[(size_t)(Nbase + waveN * 64 + ni * 16 + row16) * OLD + 2048];
  float bv[16]; int bj[16];
#pragma unroll
  for (int mi = 0; mi < 4; ++mi)
#pragma unroll
    for (int r = 0; r < 4; ++r) {
      const int e = mi * 4 + r;
      const int rg = Mbase + waveM * 64 + mi * 16 + quad * 4 + r;
      float best = 3.0e38f; int bidx = 0;  // >=3 of 4 cols valid -> always set
#pragma unroll
      for (int ni = 0; ni < 4; ++ni) {
        const int cg = Nbase + waveN * 64 + ni * 16 + row16;
        const float d = p2c[ni] - 2.0f * acc[mi][ni][r];
        if (cg != rg && d < best) { best = d; bidx = cg; }  // ni ascends: first-min
      }
      bv[e] = best; bj[e] = bidx;
    }
#pragma unroll
  for (int m = 1; m < 16; m <<= 1) {  // reduce across the 16 row16 lanes
#pragma unroll
    for (int e = 0; e < 16; ++e) {
      const float ov = __shfl_xor(bv[e], m, 64);
      const int oj = __shfl_xor(bj[e], m, 64);
      if (ov < bv[e] || (ov == bv[e] && oj < bj[e])) { bv[e] = ov; bj[e] = oj; }
    }
  }
  if (row16 == 0) {
#pragma unroll
    for (int e = 0; e < 16; ++e) {
      const int rl = waveM * 64 + (e >> 2) * 16 + quad * 4 + (e & 3);
      sval[rl][waveN] = bv[e];
      sidx[rl][waveN] = bj[e];
    }
  }
  __syncthreads();
  if (tid < 128) {
    const float v0 = sval[tid][0], v1 = sval[tid][1];
    const int j0 = sidx[tid][0], j1 = sidx[tid][1];
    const bool t1 = (v1 < v0) || (v1 == v0 && j1 < j0);
    ((float2*)&o[(size_t)(Mbase + tid) * OLD + 2056])[blockIdx.x] =
        make_float2(t1 ? v1 : v0, __int_as_float(t1 ? j1 : j0));
  }
}

// ------------- final: reduce col-block partials, gather neg row --------------
__global__ __launch_bounds__(256) void argmin_final(float* __restrict__ o, int nblk) {
  const int i = blockIdx.x, t = threadIdx.x;
  __shared__ int sj;
  if (t < 64) {
    float v = 3.4e38f; int j = 0x7fffffff;
    if (t < nblk) {
      const float2 p = ((const float2*)&o[(size_t)i * OLD + 2056])[t];
      v = p.x; j = __float_as_int(p.y);
    }
#pragma unroll
    for (int m = 32; m; m >>= 1) {
      const float ov = __shfl_xor(v, m, 64);
      const int oj = __shfl_xor(j, m, 64);
      if (ov < v || (ov == v && oj < j)) { v = ov; j = oj; }
    }
    if (t == 0) sj = (j < 0) ? 0 : (j > B - 1 ? B - 1 : j);  // clamp: never fault
  }
  __syncthreads();
  const int j = sj;
  ((float4*)&o[(size_t)i * OLD + 2048])[t] = ((const float4*)&o[(size_t)j * OLD + D])[t];
}

// ================== round-4 fallback path (fp32 vector, ws-free) =============
__global__ __launch_bounds__(256) void enc_gemm(
    const float* __restrict__ X, const float* __restrict__ W,
    const float* __restrict__ bia, float* __restrict__ out, int outOff) {
  __shared__ float lA[32][LDK];
  __shared__ float lW[32][LDK];
  const int tid = threadIdx.x;
  const int Mbase = blockIdx.y * 64;
  const int Nbase = blockIdx.x * 64;
  const int ty = tid >> 4, tx = tid & 15;
  float acc[4][4] = {};
  for (int k0 = 0; k0 < D; k0 += 32) {
    __syncthreads();
#pragma unroll
    for (int h = 0; h < 2; ++h) {
      const int ch = tid + h * 256;
      const int r = ch >> 3, c4 = (ch & 7) * 4;
      const float4 a4 = *(const float4*)&X[(size_t)(Mbase + r) * D + k0 + c4];
      lA[c4 + 0][r] = a4.x; lA[c4 + 1][r] = a4.y;
      lA[c4 + 2][r] = a4.z; lA[c4 + 3][r] = a4.w;
      const int kr = ch >> 4, nc = (ch & 15) * 4;
      *(float4*)&lW[kr][nc] = *(const float4*)&W[(size_t)(k0 + kr) * D + Nbase + nc];
    }
    __syncthreads();
#pragma unroll
    for (int kk = 0; kk < 32; ++kk) {
      const float4 av = *(const float4*)&lA[kk][ty * 4];
      const float4 wv = *(const float4*)&lW[kk][tx * 4];
      acc[0][0] += av.x * wv.x; acc[0][1] += av.x * wv.y; acc[0][2] += av.x * wv.z; acc[0][3] += av.x * wv.w;
      acc[1][0] += av.y * wv.x; acc[1][1] += av.y * wv.y; acc[1][2] += av.y * wv.z; acc[1][3] += av.y * wv.w;
      acc[2][0] += av.z * wv.x; acc[2][1] += av.z * wv.y; acc[2][2] += av.z * wv.z; acc[2][3] += av.z * wv.w;
      acc[3][0] += av.w * wv.x; acc[3][1] += av.w * wv.y; acc[3][2] += av.w * wv.z; acc[3][3] += av.w * wv.w;
    }
  }
  const float4 b4 = *(const float4*)&bia[Nbase + tx * 4];
#pragma unroll
  for (int i = 0; i < 4; ++i) {
    const int row = Mbase + ty * 4 + i;
    float4 ov;
    ov.x = acc[i][0] + b4.x; ov.y = acc[i][1] + b4.y;
    ov.z = acc[i][2] + b4.z; ov.w = acc[i][3] + b4.w;
    *(float4*)&out[(size_t)row * OLD + outOff + Nbase + tx * 4] = ov;
  }
}

__global__ __launch_bounds__(256) void dist_argmin_f32(float* __restrict__ o) {
  __shared__ float lA[32][LDK];
  __shared__ float lB[32][LDK];
  const int tid = threadIdx.x;
  const int Mbase = blockIdx.y * 64, Nbase = blockIdx.x * 64;
  const int ty = tid >> 4, tx = tid & 15;
  float acc[4][4] = {};
  for (int k0 = 0; k0 < D; k0 += 32) {
    __syncthreads();
#pragma unroll
    for (int h = 0; h < 2; ++h) {
      const int ch = tid + h * 256;
      const int r = ch >> 3, c4 = (ch & 7) * 4;
      const float4 a4 = *(const float4*)&o[(size_t)(Mbase + r) * OLD + k0 + c4];
      const float4 b4 = *(const float4*)&o[(size_t)(Nbase + r) * OLD + D + k0 + c4];
      lA[c4 + 0][r] = a4.x; lA[c4 + 1][r] = a4.y;
      lA[c4 + 2][r] = a4.z; lA[c4 + 3][r] = a4.w;
      lB[c4 + 0][r] = b4.x; lB[c4 + 1][r] = b4.y;
      lB[c4 + 2][r] = b4.z; lB[c4 + 3][r] = b4.w;
    }
    __syncthreads();
#pragma unroll
    for (int kk = 0; kk < 32; ++kk) {
      const float4 av = *(const float4*)&lA[kk][ty * 4];
      const float4 bv = *(const float4*)&lB[kk][tx * 4];
      acc[0][0] += av.x * bv.x; acc[0][1] += av.x * bv.y; acc[0][2] += av.x * bv.z; acc[0][3] += av.x * bv.w;
      acc[1][0] += av.y * bv.x; acc[1][1] += av.y * bv.y; acc[1][2] += av.y * bv.z; acc[1][3] += av.y * bv.w;
      acc[2][0] += av.z * bv.x; acc[2][1] += av.z * bv.y; acc[2][2] += av.z * bv.z; acc[2][3] += av.z * bv.w;
      acc[3][0] += av.w * bv.x; acc[3][1] += av.w * bv.y; acc[3][2] += av.w * bv.z; acc[3][3] += av.w * bv.w;
    }
  }
  float colp2[4];
#pragma unroll
  for (int j = 0; j < 4; ++j)
    colp2[j] = o[(size_t)(Nbase + tx * 4 + j) * OLD + 2048];
#pragma unroll
  for (int i = 0; i < 4; ++i) {
    const int rg = Mbase + ty * 4 + i;
    float bv = 3.0e38f; int bj = 0;
#pragma unroll
    for (int j = 0; j < 4; ++j) {
      const int cg = Nbase + tx * 4 + j;
      const float d = colp2[j] - 2.0f * acc[i][j];
      if (cg != rg && d < bv) { bv = d; bj = cg; }
    }
#pragma unroll
    for (int m = 1; m < 16; m <<= 1) {
      const float ov = __shfl_xor(bv, m, 64);
      const int oj = __shfl_xor(bj, m, 64);
      if (ov < bv || (ov == bv && oj < bj)) { bv = ov; bj = oj; }
    }
    if (tx == 0)
      ((float2*)&o[(size_t)rg * OLD + 2056])[blockIdx.x] =
          make_float2(bv, __int_as_float(bj));
  }
}

extern "C" void kernel_launch(void* const* d_in, const int* in_sizes, int n_in,
                              void* d_out, int out_size, void* d_ws, size_t ws_size,
                              hipStream_t stream) {
  const float* anchor_x = (const float*)d_in[0];  // [4096,1024] f32
  const float* pos_x    = (const float*)d_in[1];  // [4096,1024] f32
  const float* W        = (const float*)d_in[2];  // [1024,1024] f32
  const float* b        = (const float*)d_in[3];  // [1024] f32
  float* out = (float*)d_out;                     // [4096,3072] f32
  char* ws = (char*)d_ws;
  const size_t MB = 1024 * 1024;

  if (ws_size >= 52 * MB) {
    u16* Aq  = (u16*)(ws);            // [4096][3072] bf16 hi|mid|lo, 24 MB
    u16* Pq  = (u16*)(ws + 24 * MB);  // 24 MB
    u16* WtQ = (u16*)(ws + 48 * MB);  // [1024][2048] bf16 hi|mid, 4 MB
    splitT_W<<<dim3(32, 32), dim3(32, 8), 0, stream>>>(W, WtQ);
    // anchor: split X into out's dead third, encode (reads it back via DMA)
    splitX<<<B, 256, 0, stream>>>(anchor_x, (u16*)out);
    enc_mfma<<<dim3(8, 32), 256, 0, stream>>>(out, WtQ, b, 0, Aq);
    // pos: same region reused (stream-ordered after enc anchor)
    splitX<<<B, 256, 0, stream>>>(pos_x, (u16*)out);
    enc_mfma<<<dim3(8, 32), 256, 0, stream>>>(out, WtQ, b, 1024, Pq);
    pnorm<<<B, 256, 0, stream>>>(out);
    dist_mfma<<<dim3(32, 32), 256, 0, stream>>>(Aq, Pq, out);
    argmin_final<<<B, 256, 0, stream>>>(out, 32);
  } else {  // round-4 proven path: d_ws untouched
    enc_gemm<<<dim3(16, 64), 256, 0, stream>>>(anchor_x, W, b, out, 0);
    enc_gemm<<<dim3(16, 64), 256, 0, stream>>>(pos_x,    W, b, out, 1024);
    pnorm<<<B, 256, 0, stream>>>(out);
    dist_argmin_f32<<<dim3(64, 64), 256, 0, stream>>>(out);
    argmin_final<<<B, 256, 0, stream>>>(out, 64);
  }
}

// Round 7
// 348.742 us; speedup vs baseline: 2.2119x; 1.0942x over previous
//
#include <hip/hip_runtime.h>

// ---------------------------------------------------------------------------
// SiameseTripletModel: out = concat(anchor, pos, pos[argmin_j dist(i,j)])
//   anchor = anchor_x @ W + b ; pos = pos_x @ W + b   (all fp32 I/O)
//   dist[i,j] = |a_i|^2 + |p_j|^2 - 2 a_i.p_j, diagonal excluded, first-min.
//
// Round 7 (from round-6 @382us):
//   * dist pass-1: bf16 2-way split, 3 MFMA pairs (hh,hm,mh) -> ~3e-4 error,
//     tracks per-row TOP-2. 48 MFMA/iter vs 96; LDS 36KB -> 4 blocks/CU.
//   * argmin_refine: always recompute exact fp32 d for both candidates
//     (norms recomputed locally -> no cross-row dead-third reads, race-free),
//     pick lex-min, gather. True argmin misses top-2 only if 2 rivals sit
//     within ~1e-3 (P~1e-6/row).
//   * enc epilogue drops the lo chunk (Aq/Pq = hi|mid, ld 2048).
//   * all GEMM staging via global_load_lds width=16 (round-6 win).
//   * round-4 fp32 vector path kept as fallback for ws < 52 MB.
// ---------------------------------------------------------------------------

typedef short s8v __attribute__((ext_vector_type(8)));   // 8 bf16 (4 VGPRs)
typedef float f4v __attribute__((ext_vector_type(4)));   // MFMA accumulator
typedef unsigned short u16;

#define B  4096
#define D  1024
#define OLD 3072   // out leading dim (floats)
#define OLD16 6144 // out leading dim (u16)
#define LDK 68     // fallback-path LDS row (floats)

__device__ __forceinline__ u16 f2bf(float f) {
  union { float f; unsigned u; } v; v.f = f;
  unsigned r = v.u + 0x7FFFu + ((v.u >> 16) & 1u);  // RNE
  return (u16)(r >> 16);
}
__device__ __forceinline__ float bf2f(u16 s) {
  union { unsigned u; float f; } v; v.u = ((unsigned)s) << 16;
  return v.f;
}

// async 16B global->LDS (LDS dest wave-uniform; lane i lands at +16*i)
__device__ __forceinline__ void gld16(const void* g, void* l) {
  __builtin_amdgcn_global_load_lds(
      (const __attribute__((address_space(1))) unsigned int*)g,
      (__attribute__((address_space(3))) unsigned int*)l, 16, 0, 0);
}

// lexicographic top-2 of (value, index) pairs; indices are unique
struct Top2 { float v1, v2; int j1, j2; };
__device__ __forceinline__ void t2_insert(Top2& t, float v, int j) {
  if (v < t.v1 || (v == t.v1 && j < t.j1)) {
    t.v2 = t.v1; t.j2 = t.j1; t.v1 = v; t.j1 = j;
  } else if (v < t.v2 || (v == t.v2 && j < t.j2)) {
    t.v2 = v; t.j2 = j;
  }
}

// ================= W transpose + 2-way split: WtQ[n][hi k | mid k] ===========
__global__ void splitT_W(const float* __restrict__ W, u16* __restrict__ WtQ) {
  __shared__ float tile[32][33];
  const int bx = blockIdx.x * 32, by = blockIdx.y * 32;  // bx: n, by: k
  const int tx = threadIdx.x, ty = threadIdx.y;
  for (int dy = 0; dy < 32; dy += 8)
    tile[ty + dy][tx] = W[(size_t)(by + ty + dy) * D + bx + tx];
  __syncthreads();
  for (int dy = 0; dy < 32; dy += 8) {
    const float v = tile[tx][ty + dy];       // k = by+tx, n = bx+ty+dy
    const u16 h = f2bf(v);
    const size_t o = (size_t)(bx + ty + dy) * 2048 + by + tx;
    WtQ[o] = h;
    WtQ[o + 1024] = f2bf(v - bf2f(h));
  }
}

// ============ X split to bf16 hi/mid, packed into out's dead third ===========
__global__ __launch_bounds__(256) void splitX(const float* __restrict__ X,
                                              u16* __restrict__ O16) {
  const int r = blockIdx.x, t = threadIdx.x;
  const float4 v = *(const float4*)&X[(size_t)r * D + t * 4];
  const float vv[4] = {v.x, v.y, v.z, v.w};
  ushort4 hi, mi;
  u16* hp = &hi.x; u16* mp = &mi.x;
#pragma unroll
  for (int i = 0; i < 4; ++i) {
    hp[i] = f2bf(vv[i]);
    mp[i] = f2bf(vv[i] - bf2f(hp[i]));
  }
  *(ushort4*)&O16[(size_t)r * OLD16 + 4096 + t * 4] = hi;
  *(ushort4*)&O16[(size_t)r * OLD16 + 5120 + t * 4] = mi;
}

// ====== encoder MFMA GEMM: out[:,off:off+D] = X @ W + b ; Q = hi|mid =========
__global__ __launch_bounds__(256) void enc_mfma(
    float* out /* aliased: fp32 dst + u16 Xsplit src */,
    const u16* __restrict__ WtQ, const float* __restrict__ bias, int outOff,
    u16* __restrict__ Q) {
  __shared__ __align__(16) u16 lAh[128 * 32], lAm[128 * 32];
  __shared__ __align__(16) u16 lBh[128 * 32], lBm[128 * 32];
  const u16* O16 = (const u16*)out;
  const int tid = threadIdx.x, lane = tid & 63, wave = tid >> 6;
  const int waveM = wave >> 1, waveN = wave & 1;
  const int row16 = lane & 15, quad = lane >> 4;
  const int Mbase = blockIdx.y * 128;   // 32 blocks
  const int Nbase = blockIdx.x * 128;   // 8 blocks
  f4v acc[4][4] = {};

  for (int kk = 0; kk < D; kk += 32) {
    __syncthreads();
#pragma unroll
    for (int i = 0; i < 2; ++i) {
      const int c = i * 256 + wave * 64 + lane;     // 16B chunk id (0..511)
      const int row = c >> 2, col8 = (c & 3) * 8;
      const int lo = (i * 256 + wave * 64) * 8;     // wave-uniform LDS base
      gld16(&O16[(size_t)(Mbase + row) * OLD16 + 4096 + kk + col8], &lAh[lo]);
      gld16(&O16[(size_t)(Mbase + row) * OLD16 + 5120 + kk + col8], &lAm[lo]);
      gld16(&WtQ[(size_t)(Nbase + row) * 2048 + kk + col8], &lBh[lo]);
      gld16(&WtQ[(size_t)(Nbase + row) * 2048 + 1024 + kk + col8], &lBm[lo]);
    }
    __syncthreads();
    s8v ah[4], am[4], bh[4], bm[4];
#pragma unroll
    for (int mi = 0; mi < 4; ++mi) {
      const int ro = (waveM * 64 + mi * 16 + row16) * 32 + quad * 8;
      ah[mi] = *(const s8v*)&lAh[ro];
      am[mi] = *(const s8v*)&lAm[ro];
    }
#pragma unroll
    for (int ni = 0; ni < 4; ++ni) {
      const int ro = (waveN * 64 + ni * 16 + row16) * 32 + quad * 8;
      bh[ni] = *(const s8v*)&lBh[ro];
      bm[ni] = *(const s8v*)&lBm[ro];
    }
#pragma unroll
    for (int mi = 0; mi < 4; ++mi)
#pragma unroll
      for (int ni = 0; ni < 4; ++ni) {
        f4v a = acc[mi][ni];
        a = __builtin_amdgcn_mfma_f32_16x16x32_bf16(ah[mi], bh[ni], a, 0, 0, 0);
        a = __builtin_amdgcn_mfma_f32_16x16x32_bf16(ah[mi], bm[ni], a, 0, 0, 0);
        a = __builtin_amdgcn_mfma_f32_16x16x32_bf16(am[mi], bh[ni], a, 0, 0, 0);
        acc[mi][ni] = a;
      }
  }
  // C/D layout: col = lane&15, row = quad*4 + r  [m89/m91 verified]
#pragma unroll
  for (int ni = 0; ni < 4; ++ni) {
    const int col = Nbase + waveN * 64 + ni * 16 + row16;
    const float bv = bias[col];
#pragma unroll
    for (int mi = 0; mi < 4; ++mi) {
      const int rbase = Mbase + waveM * 64 + mi * 16 + quad * 4;
#pragma unroll
      for (int r = 0; r < 4; ++r) {
        const size_t row = rbase + r;
        const float v = acc[mi][ni][r] + bv;
        out[row * OLD + outOff + col] = v;
        const u16 h = f2bf(v);
        Q[row * 2048 + col] = h;
        Q[row * 2048 + 1024 + col] = f2bf(v - bf2f(h));
      }
    }
  }
}

// ---------------- pos row norms -> out[row*3072 + 2048] ----------------------
__global__ __launch_bounds__(256) void pnorm(float* __restrict__ o) {
  const int row = blockIdx.x, t = threadIdx.x;
  const float4 v = *(const float4*)&o[(size_t)row * OLD + D + t * 4];
  float s = v.x * v.x + v.y * v.y + v.z * v.z + v.w * v.w;
#pragma unroll
  for (int off = 32; off; off >>= 1) s += __shfl_down(s, off, 64);
  __shared__ float wsum[4];
  if ((t & 63) == 0) wsum[t >> 6] = s;
  __syncthreads();
  if (t == 0) o[(size_t)row * OLD + 2048] = wsum[0] + wsum[1] + wsum[2] + wsum[3];
}

// ====== dist MFMA (3 pairs: hh,hm,mh) + fused per-row TOP-2 ================
// Aq/Pq: [4096][hi|mid] bf16, ld 2048. part: float4 (v1,j1,v2,j2) per block.
__global__ __launch_bounds__(256) void dist_mfma(
    const u16* __restrict__ Aq, const u16* __restrict__ Pq, float* __restrict__ o) {
  __shared__ __align__(16) u16 lA[2][128 * 32];
  __shared__ __align__(16) u16 lB[2][128 * 32];
  __shared__ float sv1[128][2], sv2[128][2];
  __shared__ int sj1[128][2], sj2[128][2];
  const int tid = threadIdx.x, lane = tid & 63, wave = tid >> 6;
  const int waveM = wave >> 1, waveN = wave & 1;
  const int row16 = lane & 15, quad = lane >> 4;
  const int Mbase = blockIdx.y * 128;
  const int Nbase = blockIdx.x * 128;
  f4v acc[4][4] = {};

  for (int kk = 0; kk < D; kk += 32) {
    __syncthreads();
#pragma unroll
    for (int s = 0; s < 2; ++s) {
#pragma unroll
      for (int i = 0; i < 2; ++i) {
        const int c = i * 256 + wave * 64 + lane;   // 16B chunk id
        const int row = c >> 2, col8 = (c & 3) * 8;
        const int lo = (i * 256 + wave * 64) * 8;   // wave-uniform LDS base
        gld16(&Aq[(size_t)(Mbase + row) * 2048 + s * 1024 + kk + col8], &lA[s][lo]);
        gld16(&Pq[(size_t)(Nbase + row) * 2048 + s * 1024 + kk + col8], &lB[s][lo]);
      }
    }
    __syncthreads();
    s8v ah[4], am[4], bh[4], bm[4];
#pragma unroll
    for (int i = 0; i < 4; ++i) {
      const int aro = (waveM * 64 + i * 16 + row16) * 32 + quad * 8;
      const int bro = (waveN * 64 + i * 16 + row16) * 32 + quad * 8;
      ah[i] = *(const s8v*)&lA[0][aro];
      am[i] = *(const s8v*)&lA[1][aro];
      bh[i] = *(const s8v*)&lB[0][bro];
      bm[i] = *(const s8v*)&lB[1][bro];
    }
#pragma unroll
    for (int mi = 0; mi < 4; ++mi)
#pragma unroll
      for (int ni = 0; ni < 4; ++ni) {   // hh + hm + mh
        f4v a = acc[mi][ni];
        a = __builtin_amdgcn_mfma_f32_16x16x32_bf16(ah[mi], bh[ni], a, 0, 0, 0);
        a = __builtin_amdgcn_mfma_f32_16x16x32_bf16(ah[mi], bm[ni], a, 0, 0, 0);
        a = __builtin_amdgcn_mfma_f32_16x16x32_bf16(am[mi], bh[ni], a, 0, 0, 0);
        acc[mi][ni] = a;
      }
  }

  // epilogue: d = p2[col] - 2*S; per-row TOP-2 across this block's 128 cols.
  float p2c[4];
#pragma unroll
  for (int ni = 0; ni < 4; ++ni)
    p2c[ni] = o[(size_t)(Nbase + waveN * 64 + ni * 16 + row16) * OLD + 2048];
#pragma unroll
  for (int mi = 0; mi < 4; ++mi)
#pragma unroll
    for (int r = 0; r < 4; ++r) {
      const int rg = Mbase + waveM * 64 + mi * 16 + quad * 4 + r;
      Top2 tp; tp.v1 = 3.0e38f; tp.v2 = 3.0e38f; tp.j1 = 0; tp.j2 = 1;
#pragma unroll
      for (int ni = 0; ni < 4; ++ni) {
        const int cg = Nbase + waveN * 64 + ni * 16 + row16;
        if (cg != rg) t2_insert(tp, p2c[ni] - 2.0f * acc[mi][ni][r], cg);
      }
#pragma unroll
      for (int m = 1; m < 16; m <<= 1) {  // across the 16 row16 lanes
        const float ov1 = __shfl_xor(tp.v1, m, 64);
        const int oj1 = __shfl_xor(tp.j1, m, 64);
        const float ov2 = __shfl_xor(tp.v2, m, 64);
        const int oj2 = __shfl_xor(tp.j2, m, 64);
        t2_insert(tp, ov1, oj1);
        t2_insert(tp, ov2, oj2);
      }
      if (row16 == 0) {
        const int rl = waveM * 64 + mi * 16 + quad * 4 + r;
        sv1[rl][waveN] = tp.v1; sj1[rl][waveN] = tp.j1;
        sv2[rl][waveN] = tp.v2; sj2[rl][waveN] = tp.j2;
      }
    }
  __syncthreads();
  if (tid < 128) {
    Top2 tp; tp.v1 = sv1[tid][0]; tp.j1 = sj1[tid][0];
    tp.v2 = sv2[tid][0]; tp.j2 = sj2[tid][0];
    t2_insert(tp, sv1[tid][1], sj1[tid][1]);
    t2_insert(tp, sv2[tid][1], sj2[tid][1]);
    ((float4*)&o[(size_t)(Mbase + tid) * OLD + 2056])[blockIdx.x] =
        make_float4(tp.v1, __int_as_float(tp.j1), tp.v2, __int_as_float(tp.j2));
  }
}

// ===== final: global top-2, EXACT fp32 refine, gather neg row ================
__global__ __launch_bounds__(256) void argmin_refine(float* __restrict__ o) {
  const int i = blockIdx.x, t = threadIdx.x;
  __shared__ int gj[2];
  if (t < 32) {
    const float4 p = ((const float4*)&o[(size_t)i * OLD + 2056])[t];
    Top2 tp; tp.v1 = p.x; tp.j1 = __float_as_int(p.y);
    tp.v2 = p.z; tp.j2 = __float_as_int(p.w);
#pragma unroll
    for (int m = 1; m < 32; m <<= 1) {
      const float ov1 = __shfl_xor(tp.v1, m, 64);
      const int oj1 = __shfl_xor(tp.j1, m, 64);
      const float ov2 = __shfl_xor(tp.v2, m, 64);
      const int oj2 = __shfl_xor(tp.j2, m, 64);
      t2_insert(tp, ov1, oj1);
      t2_insert(tp, ov2, oj2);
    }
    if (t == 0) {
      gj[0] = (tp.j1 < 0) ? 0 : (tp.j1 > B - 1 ? B - 1 : tp.j1);  // clamp: no fault
      gj[1] = (tp.j2 < 0) ? 0 : (tp.j2 > B - 1 ? B - 1 : tp.j2);
    }
  }
  __syncthreads();
  const int j1 = gj[0], j2 = gj[1];
  // exact fp32: d = |p_j|^2 - 2 a_i.p_j (norms recomputed -> no cross-row
  // reads of the dead third; race-free vs other blocks' gathers)
  const float4 a4 = *(const float4*)&o[(size_t)i * OLD + t * 4];
  const float4 q1 = *(const float4*)&o[(size_t)j1 * OLD + D + t * 4];
  const float4 q2 = *(const float4*)&o[(size_t)j2 * OLD + D + t * 4];
  float s1 = a4.x * q1.x + a4.y * q1.y + a4.z * q1.z + a4.w * q1.w;
  float s2 = a4.x * q2.x + a4.y * q2.y + a4.z * q2.z + a4.w * q2.w;
  float n1 = q1.x * q1.x + q1.y * q1.y + q1.z * q1.z + q1.w * q1.w;
  float n2 = q2.x * q2.x + q2.y * q2.y + q2.z * q2.z + q2.w * q2.w;
#pragma unroll
  for (int off = 32; off; off >>= 1) {
    s1 += __shfl_down(s1, off, 64);
    s2 += __shfl_down(s2, off, 64);
    n1 += __shfl_down(n1, off, 64);
    n2 += __shfl_down(n2, off, 64);
  }
  __shared__ float wsum[4][4];
  __shared__ int sjf;
  if ((t & 63) == 0) {
    wsum[t >> 6][0] = s1; wsum[t >> 6][1] = s2;
    wsum[t >> 6][2] = n1; wsum[t >> 6][3] = n2;
  }
  __syncthreads();
  if (t == 0) {
    const float S1 = wsum[0][0] + wsum[1][0] + wsum[2][0] + wsum[3][0];
    const float S2 = wsum[0][1] + wsum[1][1] + wsum[2][1] + wsum[3][1];
    const float N1 = wsum[0][2] + wsum[1][2] + wsum[2][2] + wsum[3][2];
    const float N2 = wsum[0][3] + wsum[1][3] + wsum[2][3] + wsum[3][3];
    const float d1 = N1 - 2.0f * S1, d2 = N2 - 2.0f * S2;
    sjf = (d2 < d1 || (d2 == d1 && j2 < j1)) ? j2 : j1;
  }
  __syncthreads();
  const int j = sjf;
  ((float4*)&o[(size_t)i * OLD + 2048])[t] = ((const float4*)&o[(size_t)j * OLD + D])[t];
}

// ================== round-4 fallback path (fp32 vector, ws-free) =============
__global__ __launch_bounds__(256) void enc_gemm(
    const float* __restrict__ X, const float* __restrict__ W,
    const float* __restrict__ bia, float* __restrict__ out, int outOff) {
  __shared__ float lA[32][LDK];
  __shared__ float lW[32][LDK];
  const int tid = threadIdx.x;
  const int Mbase = blockIdx.y * 64;
  const int Nbase = blockIdx.x * 64;
  const int ty = tid >> 4, tx = tid & 15;
  float acc[4][4] = {};
  for (int k0 = 0; k0 < D; k0 += 32) {
    __syncthreads();
#pragma unroll
    for (int h = 0; h < 2; ++h) {
      const int ch = tid + h * 256;
      const int r = ch >> 3, c4 = (ch & 7) * 4;
      const float4 a4 = *(const float4*)&X[(size_t)(Mbase + r) * D + k0 + c4];
      lA[c4 + 0][r] = a4.x; lA[c4 + 1][r] = a4.y;
      lA[c4 + 2][r] = a4.z; lA[c4 + 3][r] = a4.w;
      const int kr = ch >> 4, nc = (ch & 15) * 4;
      *(float4*)&lW[kr][nc] = *(const float4*)&W[(size_t)(k0 + kr) * D + Nbase + nc];
    }
    __syncthreads();
#pragma unroll
    for (int kk = 0; kk < 32; ++kk) {
      const float4 av = *(const float4*)&lA[kk][ty * 4];
      const float4 wv = *(const float4*)&lW[kk][tx * 4];
      acc[0][0] += av.x * wv.x; acc[0][1] += av.x * wv.y; acc[0][2] += av.x * wv.z; acc[0][3] += av.x * wv.w;
      acc[1][0] += av.y * wv.x; acc[1][1] += av.y * wv.y; acc[1][2] += av.y * wv.z; acc[1][3] += av.y * wv.w;
      acc[2][0] += av.z * wv.x; acc[2][1] += av.z * wv.y; acc[2][2] += av.z * wv.z; acc[2][3] += av.z * wv.w;
      acc[3][0] += av.w * wv.x; acc[3][1] += av.w * wv.y; acc[3][2] += av.w * wv.z; acc[3][3] += av.w * wv.w;
    }
  }
  const float4 b4 = *(const float4*)&bia[Nbase + tx * 4];
#pragma unroll
  for (int i = 0; i < 4; ++i) {
    const int row = Mbase + ty * 4 + i;
    float4 ov;
    ov.x = acc[i][0] + b4.x; ov.y = acc[i][1] + b4.y;
    ov.z = acc[i][2] + b4.z; ov.w = acc[i][3] + b4.w;
    *(float4*)&out[(size_t)row * OLD + outOff + Nbase + tx * 4] = ov;
  }
}

__global__ __launch_bounds__(256) void dist_argmin_f32(float* __restrict__ o) {
  __shared__ float lA[32][LDK];
  __shared__ float lB[32][LDK];
  const int tid = threadIdx.x;
  const int Mbase = blockIdx.y * 64, Nbase = blockIdx.x * 64;
  const int ty = tid >> 4, tx = tid & 15;
  float acc[4][4] = {};
  for (int k0 = 0; k0 < D; k0 += 32) {
    __syncthreads();
#pragma unroll
    for (int h = 0; h < 2; ++h) {
      const int ch = tid + h * 256;
      const int r = ch >> 3, c4 = (ch & 7) * 4;
      const float4 a4 = *(const float4*)&o[(size_t)(Mbase + r) * OLD + k0 + c4];
      const float4 b4 = *(const float4*)&o[(size_t)(Nbase + r) * OLD + D + k0 + c4];
      lA[c4 + 0][r] = a4.x; lA[c4 + 1][r] = a4.y;
      lA[c4 + 2][r] = a4.z; lA[c4 + 3][r] = a4.w;
      lB[c4 + 0][r] = b4.x; lB[c4 + 1][r] = b4.y;
      lB[c4 + 2][r] = b4.z; lB[c4 + 3][r] = b4.w;
    }
    __syncthreads();
#pragma unroll
    for (int kk = 0; kk < 32; ++kk) {
      const float4 av = *(const float4*)&lA[kk][ty * 4];
      const float4 bv = *(const float4*)&lB[kk][tx * 4];
      acc[0][0] += av.x * bv.x; acc[0][1] += av.x * bv.y; acc[0][2] += av.x * bv.z; acc[0][3] += av.x * bv.w;
      acc[1][0] += av.y * bv.x; acc[1][1] += av.y * bv.y; acc[1][2] += av.y * bv.z; acc[1][3] += av.y * bv.w;
      acc[2][0] += av.z * bv.x; acc[2][1] += av.z * bv.y; acc[2][2] += av.z * bv.z; acc[2][3] += av.z * bv.w;
      acc[3][0] += av.w * bv.x; acc[3][1] += av.w * bv.y; acc[3][2] += av.w * bv.z; acc[3][3] += av.w * bv.w;
    }
  }
  float colp2[4];
#pragma unroll
  for (int j = 0; j < 4; ++j)
    colp2[j] = o[(size_t)(Nbase + tx * 4 + j) * OLD + 2048];
#pragma unroll
  for (int i = 0; i < 4; ++i) {
    const int rg = Mbase + ty * 4 + i;
    float bv = 3.0e38f; int bj = 0;
#pragma unroll
    for (int j = 0; j < 4; ++j) {
      const int cg = Nbase + tx * 4 + j;
      const float d = colp2[j] - 2.0f * acc[i][j];
      if (cg != rg && d < bv) { bv = d; bj = cg; }
    }
#pragma unroll
    for (int m = 1; m < 16; m <<= 1) {
      const float ov = __shfl_xor(bv, m, 64);
      const int oj = __shfl_xor(bj, m, 64);
      if (ov < bv || (ov == bv && oj < bj)) { bv = ov; bj = oj; }
    }
    if (tx == 0)
      ((float2*)&o[(size_t)rg * OLD + 2056])[blockIdx.x] =
          make_float2(bv, __int_as_float(bj));
  }
}

__global__ __launch_bounds__(256) void argmin_final_f2(float* __restrict__ o, int nblk) {
  const int i = blockIdx.x, t = threadIdx.x;
  __shared__ int sj;
  if (t < 64) {
    float v = 3.4e38f; int j = 0x7fffffff;
    if (t < nblk) {
      const float2 p = ((const float2*)&o[(size_t)i * OLD + 2056])[t];
      v = p.x; j = __float_as_int(p.y);
    }
#pragma unroll
    for (int m = 32; m; m >>= 1) {
      const float ov = __shfl_xor(v, m, 64);
      const int oj = __shfl_xor(j, m, 64);
      if (ov < v || (ov == v && oj < j)) { v = ov; j = oj; }
    }
    if (t == 0) sj = (j < 0) ? 0 : (j > B - 1 ? B - 1 : j);
  }
  __syncthreads();
  const int j = sj;
  ((float4*)&o[(size_t)i * OLD + 2048])[t] = ((const float4*)&o[(size_t)j * OLD + D])[t];
}

extern "C" void kernel_launch(void* const* d_in, const int* in_sizes, int n_in,
                              void* d_out, int out_size, void* d_ws, size_t ws_size,
                              hipStream_t stream) {
  const float* anchor_x = (const float*)d_in[0];  // [4096,1024] f32
  const float* pos_x    = (const float*)d_in[1];  // [4096,1024] f32
  const float* W        = (const float*)d_in[2];  // [1024,1024] f32
  const float* b        = (const float*)d_in[3];  // [1024] f32
  float* out = (float*)d_out;                     // [4096,3072] f32
  char* ws = (char*)d_ws;
  const size_t MB = 1024 * 1024;

  if (ws_size >= 52 * MB) {  // uses only 36 MB; 52 threshold proven rounds 5-6
    u16* Aq  = (u16*)(ws);            // [4096][2048] bf16 hi|mid, 16 MB
    u16* Pq  = (u16*)(ws + 16 * MB);  // 16 MB
    u16* WtQ = (u16*)(ws + 32 * MB);  // [1024][2048] bf16 hi|mid, 4 MB
    splitT_W<<<dim3(32, 32), dim3(32, 8), 0, stream>>>(W, WtQ);
    splitX<<<B, 256, 0, stream>>>(anchor_x, (u16*)out);
    enc_mfma<<<dim3(8, 32), 256, 0, stream>>>(out, WtQ, b, 0, Aq);
    splitX<<<B, 256, 0, stream>>>(pos_x, (u16*)out);
    enc_mfma<<<dim3(8, 32), 256, 0, stream>>>(out, WtQ, b, 1024, Pq);
    pnorm<<<B, 256, 0, stream>>>(out);
    dist_mfma<<<dim3(32, 32), 256, 0, stream>>>(Aq, Pq, out);
    argmin_refine<<<B, 256, 0, stream>>>(out);
  } else {  // round-4 proven path: d_ws untouched
    enc_gemm<<<dim3(16, 64), 256, 0, stream>>>(anchor_x, W, b, out, 0);
    enc_gemm<<<dim3(16, 64), 256, 0, stream>>>(pos_x,    W, b, out, 1024);
    pnorm<<<B, 256, 0, stream>>>(out);
    dist_argmin_f32<<<dim3(64, 64), 256, 0, stream>>>(out);
    argmin_final_f2<<<B, 256, 0, stream>>>(out, 64);
  }
}

// Round 8
// 336.275 us; speedup vs baseline: 2.2939x; 1.0371x over previous
//
#include <hip/hip_runtime.h>

// ---------------------------------------------------------------------------
// SiameseTripletModel: out = concat(anchor, pos, pos[argmin_j dist(i,j)])
//   anchor = anchor_x @ W + b ; pos = pos_x @ W + b   (all fp32 I/O)
//   dist[i,j] = |p_j|^2 - 2 a_i.p_j (+|a_i|^2 const), diag excluded, first-min.
//
// Round 8 (from round-7 @349us):
//   * dist pass-1: 2 MFMA pairs (A = hi+mid "full 16-bit", B = hi only)
//     -> error ~0.065 vs gap scale ~17; 68.7 GF, LDS 28 KB.
//   * per-block top-2 partials -> global TOP-4 -> exact fp32 refine (4 dots).
//   * one merged splitX (anchor -> out dead third, pos -> ws+36MB) and ONE
//     merged encoder dispatch (grid 8x64; blockIdx.y selects anchor/pos).
//   * encoder stays 3-pair (activation accuracy bounds argmin flips).
//   * round-4 fp32 vector path kept as fallback for ws < 52 MB.
// ---------------------------------------------------------------------------

typedef short s8v __attribute__((ext_vector_type(8)));   // 8 bf16 (4 VGPRs)
typedef float f4v __attribute__((ext_vector_type(4)));   // MFMA accumulator
typedef unsigned short u16;

#define B  4096
#define D  1024
#define OLD 3072   // out leading dim (floats)
#define OLD16 6144 // out leading dim (u16)
#define LDK 68     // fallback-path LDS row (floats)

__device__ __forceinline__ u16 f2bf(float f) {
  union { float f; unsigned u; } v; v.f = f;
  unsigned r = v.u + 0x7FFFu + ((v.u >> 16) & 1u);  // RNE
  return (u16)(r >> 16);
}
__device__ __forceinline__ float bf2f(u16 s) {
  union { unsigned u; float f; } v; v.u = ((unsigned)s) << 16;
  return v.f;
}

// async 16B global->LDS (LDS dest wave-uniform; lane i lands at +16*i)
__device__ __forceinline__ void gld16(const void* g, void* l) {
  __builtin_amdgcn_global_load_lds(
      (const __attribute__((address_space(1))) unsigned int*)g,
      (__attribute__((address_space(3))) unsigned int*)l, 16, 0, 0);
}

// lexicographic top-2 / top-4 of (value, index); indices unique by construction
struct Top2 { float v1, v2; int j1, j2; };
__device__ __forceinline__ void t2_insert(Top2& t, float v, int j) {
  if (v < t.v1 || (v == t.v1 && j < t.j1)) {
    t.v2 = t.v1; t.j2 = t.j1; t.v1 = v; t.j1 = j;
  } else if (v < t.v2 || (v == t.v2 && j < t.j2)) {
    t.v2 = v; t.j2 = j;
  }
}
struct Top4 { float v[4]; int j[4]; };
__device__ __forceinline__ void t4_insert(Top4& t, float v, int j) {
  if (v < t.v[3] || (v == t.v[3] && j < t.j[3])) {
    int p = 3;
#pragma unroll
    for (int s = 0; s < 3; ++s) {
      if (p > 0 && (v < t.v[p - 1] || (v == t.v[p - 1] && j < t.j[p - 1]))) {
        t.v[p] = t.v[p - 1]; t.j[p] = t.j[p - 1]; --p;
      }
    }
    t.v[p] = v; t.j[p] = j;
  }
}

// ================= W transpose + 2-way split: WtQ[n][hi k | mid k] ===========
__global__ void splitT_W(const float* __restrict__ W, u16* __restrict__ WtQ) {
  __shared__ float tile[32][33];
  const int bx = blockIdx.x * 32, by = blockIdx.y * 32;  // bx: n, by: k
  const int tx = threadIdx.x, ty = threadIdx.y;
  for (int dy = 0; dy < 32; dy += 8)
    tile[ty + dy][tx] = W[(size_t)(by + ty + dy) * D + bx + tx];
  __syncthreads();
  for (int dy = 0; dy < 32; dy += 8) {
    const float v = tile[tx][ty + dy];       // k = by+tx, n = bx+ty+dy
    const u16 h = f2bf(v);
    const size_t o = (size_t)(bx + ty + dy) * 2048 + by + tx;
    WtQ[o] = h;
    WtQ[o + 1024] = f2bf(v - bf2f(h));
  }
}

// ==== X split to bf16 hi/mid: anchor -> out dead third, pos -> posXq (ws) ====
__global__ __launch_bounds__(256) void splitX2(
    const float* __restrict__ A, const float* __restrict__ P,
    u16* __restrict__ O16, u16* __restrict__ posXq) {
  const int r = blockIdx.x, t = threadIdx.x;
  const bool isPos = r >= B;
  const int row = isPos ? r - B : r;
  const float4 v = *(const float4*)&(isPos ? P : A)[(size_t)row * D + t * 4];
  const float vv[4] = {v.x, v.y, v.z, v.w};
  ushort4 hi, mi;
  u16* hp = &hi.x; u16* mp = &mi.x;
#pragma unroll
  for (int i = 0; i < 4; ++i) {
    hp[i] = f2bf(vv[i]);
    mp[i] = f2bf(vv[i] - bf2f(hp[i]));
  }
  if (isPos) {
    *(ushort4*)&posXq[(size_t)row * 2048 + t * 4] = hi;
    *(ushort4*)&posXq[(size_t)row * 2048 + 1024 + t * 4] = mi;
  } else {
    *(ushort4*)&O16[(size_t)row * OLD16 + 4096 + t * 4] = hi;
    *(ushort4*)&O16[(size_t)row * OLD16 + 5120 + t * 4] = mi;
  }
}

// ====== merged encoder MFMA GEMM (anchor + pos in one dispatch) =============
// blockIdx.y < 32: anchor rows (A from out dead third); else pos (from posXq).
// 3 term-pairs hh+hm+mh. Writes fp32 activations + bf16 hi|mid Q.
__global__ __launch_bounds__(256) void enc_mfma(
    float* out, const u16* __restrict__ posXq, const u16* __restrict__ WtQ,
    const float* __restrict__ bias, u16* __restrict__ Aq, u16* __restrict__ Pq) {
  __shared__ __align__(16) u16 lAh[128 * 32], lAm[128 * 32];
  __shared__ __align__(16) u16 lBh[128 * 32], lBm[128 * 32];
  const u16* O16 = (const u16*)out;
  const int tid = threadIdx.x, lane = tid & 63, wave = tid >> 6;
  const int waveM = wave >> 1, waveN = wave & 1;
  const int row16 = lane & 15, quad = lane >> 4;
  const bool isPos = blockIdx.y >= 32;
  const int Mbase = (blockIdx.y & 31) * 128;
  const int Nbase = blockIdx.x * 128;   // 8 blocks
  f4v acc[4][4] = {};

  for (int kk = 0; kk < D; kk += 32) {
    __syncthreads();
#pragma unroll
    for (int i = 0; i < 2; ++i) {
      const int c = i * 256 + wave * 64 + lane;     // 16B chunk id (0..511)
      const int row = c >> 2, col8 = (c & 3) * 8;
      const int lo = (i * 256 + wave * 64) * 8;     // wave-uniform LDS base
      if (isPos) {
        gld16(&posXq[(size_t)(Mbase + row) * 2048 + kk + col8], &lAh[lo]);
        gld16(&posXq[(size_t)(Mbase + row) * 2048 + 1024 + kk + col8], &lAm[lo]);
      } else {
        gld16(&O16[(size_t)(Mbase + row) * OLD16 + 4096 + kk + col8], &lAh[lo]);
        gld16(&O16[(size_t)(Mbase + row) * OLD16 + 5120 + kk + col8], &lAm[lo]);
      }
      gld16(&WtQ[(size_t)(Nbase + row) * 2048 + kk + col8], &lBh[lo]);
      gld16(&WtQ[(size_t)(Nbase + row) * 2048 + 1024 + kk + col8], &lBm[lo]);
    }
    __syncthreads();
    s8v ah[4], am[4], bh[4], bm[4];
#pragma unroll
    for (int mi = 0; mi < 4; ++mi) {
      const int ro = (waveM * 64 + mi * 16 + row16) * 32 + quad * 8;
      ah[mi] = *(const s8v*)&lAh[ro];
      am[mi] = *(const s8v*)&lAm[ro];
    }
#pragma unroll
    for (int ni = 0; ni < 4; ++ni) {
      const int ro = (waveN * 64 + ni * 16 + row16) * 32 + quad * 8;
      bh[ni] = *(const s8v*)&lBh[ro];
      bm[ni] = *(const s8v*)&lBm[ro];
    }
#pragma unroll
    for (int mi = 0; mi < 4; ++mi)
#pragma unroll
      for (int ni = 0; ni < 4; ++ni) {
        f4v a = acc[mi][ni];
        a = __builtin_amdgcn_mfma_f32_16x16x32_bf16(ah[mi], bh[ni], a, 0, 0, 0);
        a = __builtin_amdgcn_mfma_f32_16x16x32_bf16(ah[mi], bm[ni], a, 0, 0, 0);
        a = __builtin_amdgcn_mfma_f32_16x16x32_bf16(am[mi], bh[ni], a, 0, 0, 0);
        acc[mi][ni] = a;
      }
  }
  // C/D layout: col = lane&15, row = quad*4 + r  [m89/m91 verified]
  const int outOff = isPos ? 1024 : 0;
  u16* Q = isPos ? Pq : Aq;
#pragma unroll
  for (int ni = 0; ni < 4; ++ni) {
    const int col = Nbase + waveN * 64 + ni * 16 + row16;
    const float bv = bias[col];
#pragma unroll
    for (int mi = 0; mi < 4; ++mi) {
      const int rbase = Mbase + waveM * 64 + mi * 16 + quad * 4;
#pragma unroll
      for (int r = 0; r < 4; ++r) {
        const size_t row = rbase + r;
        const float v = acc[mi][ni][r] + bv;
        out[row * OLD + outOff + col] = v;
        const u16 h = f2bf(v);
        Q[row * 2048 + col] = h;
        Q[row * 2048 + 1024 + col] = f2bf(v - bf2f(h));
      }
    }
  }
}

// ---------------- pos row norms -> out[row*3072 + 2048] ----------------------
__global__ __launch_bounds__(256) void pnorm(float* __restrict__ o) {
  const int row = blockIdx.x, t = threadIdx.x;
  const float4 v = *(const float4*)&o[(size_t)row * OLD + D + t * 4];
  float s = v.x * v.x + v.y * v.y + v.z * v.z + v.w * v.w;
#pragma unroll
  for (int off = 32; off; off >>= 1) s += __shfl_down(s, off, 64);
  __shared__ float wsum[4];
  if ((t & 63) == 0) wsum[t >> 6] = s;
  __syncthreads();
  if (t == 0) o[(size_t)row * OLD + 2048] = wsum[0] + wsum[1] + wsum[2] + wsum[3];
}

// ====== dist MFMA (2 pairs: a_full x p_hi) + fused per-row TOP-2 ============
// Aq: hi|mid (both staged); Pq: hi only. part: float4 (v1,j1,v2,j2) per block.
__global__ __launch_bounds__(256) void dist_mfma(
    const u16* __restrict__ Aq, const u16* __restrict__ Pq, float* __restrict__ o) {
  __shared__ __align__(16) u16 lAh[128 * 32], lAm[128 * 32];
  __shared__ __align__(16) u16 lBh[128 * 32];
  __shared__ float sv1[128][2], sv2[128][2];
  __shared__ int sj1[128][2], sj2[128][2];
  const int tid = threadIdx.x, lane = tid & 63, wave = tid >> 6;
  const int waveM = wave >> 1, waveN = wave & 1;
  const int row16 = lane & 15, quad = lane >> 4;
  const int Mbase = blockIdx.y * 128;
  const int Nbase = blockIdx.x * 128;
  f4v acc[4][4] = {};

  for (int kk = 0; kk < D; kk += 32) {
    __syncthreads();
#pragma unroll
    for (int i = 0; i < 2; ++i) {
      const int c = i * 256 + wave * 64 + lane;   // 16B chunk id
      const int row = c >> 2, col8 = (c & 3) * 8;
      const int lo = (i * 256 + wave * 64) * 8;   // wave-uniform LDS base
      gld16(&Aq[(size_t)(Mbase + row) * 2048 + kk + col8], &lAh[lo]);
      gld16(&Aq[(size_t)(Mbase + row) * 2048 + 1024 + kk + col8], &lAm[lo]);
      gld16(&Pq[(size_t)(Nbase + row) * 2048 + kk + col8], &lBh[lo]);
    }
    __syncthreads();
    s8v ah[4], am[4], bh[4];
#pragma unroll
    for (int i = 0; i < 4; ++i) {
      const int aro = (waveM * 64 + i * 16 + row16) * 32 + quad * 8;
      const int bro = (waveN * 64 + i * 16 + row16) * 32 + quad * 8;
      ah[i] = *(const s8v*)&lAh[aro];
      am[i] = *(const s8v*)&lAm[aro];
      bh[i] = *(const s8v*)&lBh[bro];
    }
#pragma unroll
    for (int mi = 0; mi < 4; ++mi)
#pragma unroll
      for (int ni = 0; ni < 4; ++ni) {   // (ah + am) * bh
        f4v a = acc[mi][ni];
        a = __builtin_amdgcn_mfma_f32_16x16x32_bf16(ah[mi], bh[ni], a, 0, 0, 0);
        a = __builtin_amdgcn_mfma_f32_16x16x32_bf16(am[mi], bh[ni], a, 0, 0, 0);
        acc[mi][ni] = a;
      }
  }

  // epilogue: d = p2[col] - 2*S; per-row TOP-2 across this block's 128 cols.
  float p2c[4];
#pragma unroll
  for (int ni = 0; ni < 4; ++ni)
    p2c[ni] = o[(size_t)(Nbase + waveN * 64 + ni * 16 + row16) * OLD + 2048];
#pragma unroll
  for (int mi = 0; mi < 4; ++mi)
#pragma unroll
    for (int r = 0; r < 4; ++r) {
      const int rg = Mbase + waveM * 64 + mi * 16 + quad * 4 + r;
      Top2 tp; tp.v1 = 3.0e38f; tp.v2 = 3.0e38f; tp.j1 = 0; tp.j2 = 1;
#pragma unroll
      for (int ni = 0; ni < 4; ++ni) {
        const int cg = Nbase + waveN * 64 + ni * 16 + row16;
        if (cg != rg) t2_insert(tp, p2c[ni] - 2.0f * acc[mi][ni][r], cg);
      }
#pragma unroll
      for (int m = 1; m < 16; m <<= 1) {  // across the 16 row16 lanes
        const float ov1 = __shfl_xor(tp.v1, m, 64);
        const int oj1 = __shfl_xor(tp.j1, m, 64);
        const float ov2 = __shfl_xor(tp.v2, m, 64);
        const int oj2 = __shfl_xor(tp.j2, m, 64);
        t2_insert(tp, ov1, oj1);
        t2_insert(tp, ov2, oj2);
      }
      if (row16 == 0) {
        const int rl = waveM * 64 + mi * 16 + quad * 4 + r;
        sv1[rl][waveN] = tp.v1; sj1[rl][waveN] = tp.j1;
        sv2[rl][waveN] = tp.v2; sj2[rl][waveN] = tp.j2;
      }
    }
  __syncthreads();
  if (tid < 128) {
    Top2 tp; tp.v1 = sv1[tid][0]; tp.j1 = sj1[tid][0];
    tp.v2 = sv2[tid][0]; tp.j2 = sj2[tid][0];
    t2_insert(tp, sv1[tid][1], sj1[tid][1]);
    t2_insert(tp, sv2[tid][1], sj2[tid][1]);
    ((float4*)&o[(size_t)(Mbase + tid) * OLD + 2056])[blockIdx.x] =
        make_float4(tp.v1, __int_as_float(tp.j1), tp.v2, __int_as_float(tp.j2));
  }
}

// ===== final: global TOP-4, EXACT fp32 refine, gather neg row ================
__global__ __launch_bounds__(256) void argmin_refine(float* __restrict__ o) {
  const int i = blockIdx.x, t = threadIdx.x;
  __shared__ int gj[4];
  if (t < 64) {
    Top4 tp;
#pragma unroll
    for (int c = 0; c < 4; ++c) { tp.v[c] = 3.0e38f; tp.j[c] = 0; }
    if (t < 32) {
      const float4 p = ((const float4*)&o[(size_t)i * OLD + 2056])[t];
      t4_insert(tp, p.x, __float_as_int(p.y));
      t4_insert(tp, p.z, __float_as_int(p.w));
    }
#pragma unroll
    for (int m = 1; m < 32; m <<= 1) {
#pragma unroll
      for (int c = 0; c < 4; ++c) {
        const float ov = __shfl_xor(tp.v[c], m, 64);
        const int oj = __shfl_xor(tp.j[c], m, 64);
        t4_insert(tp, ov, oj);
      }
    }
    if (t == 0) {
#pragma unroll
      for (int c = 0; c < 4; ++c)
        gj[c] = (tp.j[c] < 0) ? 0 : (tp.j[c] > B - 1 ? B - 1 : tp.j[c]);  // clamp
    }
  }
  __syncthreads();
  int jj[4];
#pragma unroll
  for (int c = 0; c < 4; ++c) jj[c] = gj[c];
  // exact fp32: d_c = |p_jc|^2 - 2 a_i.p_jc (norms recomputed locally)
  const float4 a4 = *(const float4*)&o[(size_t)i * OLD + t * 4];
  float s[4], n[4];
#pragma unroll
  for (int c = 0; c < 4; ++c) {
    const float4 q = *(const float4*)&o[(size_t)jj[c] * OLD + D + t * 4];
    s[c] = a4.x * q.x + a4.y * q.y + a4.z * q.z + a4.w * q.w;
    n[c] = q.x * q.x + q.y * q.y + q.z * q.z + q.w * q.w;
  }
#pragma unroll
  for (int off = 32; off; off >>= 1)
#pragma unroll
    for (int c = 0; c < 4; ++c) {
      s[c] += __shfl_down(s[c], off, 64);
      n[c] += __shfl_down(n[c], off, 64);
    }
  __shared__ float wsum[4][8];
  __shared__ int sjf;
  if ((t & 63) == 0)
#pragma unroll
    for (int c = 0; c < 4; ++c) {
      wsum[t >> 6][c] = s[c];
      wsum[t >> 6][4 + c] = n[c];
    }
  __syncthreads();
  if (t == 0) {
    float bd = 3.4e38f; int bj = 0x7fffffff;
#pragma unroll
    for (int c = 0; c < 4; ++c) {
      const float S = wsum[0][c] + wsum[1][c] + wsum[2][c] + wsum[3][c];
      const float N = wsum[0][4 + c] + wsum[1][4 + c] + wsum[2][4 + c] + wsum[3][4 + c];
      const float d = N - 2.0f * S;
      const int j = jj[c];
      if (d < bd || (d == bd && j < bj)) { bd = d; bj = j; }
    }
    sjf = bj;
  }
  __syncthreads();
  const int j = sjf;
  ((float4*)&o[(size_t)i * OLD + 2048])[t] = ((const float4*)&o[(size_t)j * OLD + D])[t];
}

// ================== round-4 fallback path (fp32 vector, ws-free) =============
__global__ __launch_bounds__(256) void enc_gemm(
    const float* __restrict__ X, const float* __restrict__ W,
    const float* __restrict__ bia, float* __restrict__ out, int outOff) {
  __shared__ float lA[32][LDK];
  __shared__ float lW[32][LDK];
  const int tid = threadIdx.x;
  const int Mbase = blockIdx.y * 64;
  const int Nbase = blockIdx.x * 64;
  const int ty = tid >> 4, tx = tid & 15;
  float acc[4][4] = {};
  for (int k0 = 0; k0 < D; k0 += 32) {
    __syncthreads();
#pragma unroll
    for (int h = 0; h < 2; ++h) {
      const int ch = tid + h * 256;
      const int r = ch >> 3, c4 = (ch & 7) * 4;
      const float4 a4 = *(const float4*)&X[(size_t)(Mbase + r) * D + k0 + c4];
      lA[c4 + 0][r] = a4.x; lA[c4 + 1][r] = a4.y;
      lA[c4 + 2][r] = a4.z; lA[c4 + 3][r] = a4.w;
      const int kr = ch >> 4, nc = (ch & 15) * 4;
      *(float4*)&lW[kr][nc] = *(const float4*)&W[(size_t)(k0 + kr) * D + Nbase + nc];
    }
    __syncthreads();
#pragma unroll
    for (int kk = 0; kk < 32; ++kk) {
      const float4 av = *(const float4*)&lA[kk][ty * 4];
      const float4 wv = *(const float4*)&lW[kk][tx * 4];
      acc[0][0] += av.x * wv.x; acc[0][1] += av.x * wv.y; acc[0][2] += av.x * wv.z; acc[0][3] += av.x * wv.w;
      acc[1][0] += av.y * wv.x; acc[1][1] += av.y * wv.y; acc[1][2] += av.y * wv.z; acc[1][3] += av.y * wv.w;
      acc[2][0] += av.z * wv.x; acc[2][1] += av.z * wv.y; acc[2][2] += av.z * wv.z; acc[2][3] += av.z * wv.w;
      acc[3][0] += av.w * wv.x; acc[3][1] += av.w * wv.y; acc[3][2] += av.w * wv.z; acc[3][3] += av.w * wv.w;
    }
  }
  const float4 b4 = *(const float4*)&bia[Nbase + tx * 4];
#pragma unroll
  for (int i = 0; i < 4; ++i) {
    const int row = Mbase + ty * 4 + i;
    float4 ov;
    ov.x = acc[i][0] + b4.x; ov.y = acc[i][1] + b4.y;
    ov.z = acc[i][2] + b4.z; ov.w = acc[i][3] + b4.w;
    *(float4*)&out[(size_t)row * OLD + outOff + Nbase + tx * 4] = ov;
  }
}

__global__ __launch_bounds__(256) void dist_argmin_f32(float* __restrict__ o) {
  __shared__ float lA[32][LDK];
  __shared__ float lB[32][LDK];
  const int tid = threadIdx.x;
  const int Mbase = blockIdx.y * 64, Nbase = blockIdx.x * 64;
  const int ty = tid >> 4, tx = tid & 15;
  float acc[4][4] = {};
  for (int k0 = 0; k0 < D; k0 += 32) {
    __syncthreads();
#pragma unroll
    for (int h = 0; h < 2; ++h) {
      const int ch = tid + h * 256;
      const int r = ch >> 3, c4 = (ch & 7) * 4;
      const float4 a4 = *(const float4*)&o[(size_t)(Mbase + r) * OLD + k0 + c4];
      const float4 b4 = *(const float4*)&o[(size_t)(Nbase + r) * OLD + D + k0 + c4];
      lA[c4 + 0][r] = a4.x; lA[c4 + 1][r] = a4.y;
      lA[c4 + 2][r] = a4.z; lA[c4 + 3][r] = a4.w;
      lB[c4 + 0][r] = b4.x; lB[c4 + 1][r] = b4.y;
      lB[c4 + 2][r] = b4.z; lB[c4 + 3][r] = b4.w;
    }
    __syncthreads();
#pragma unroll
    for (int kk = 0; kk < 32; ++kk) {
      const float4 av = *(const float4*)&lA[kk][ty * 4];
      const float4 bv = *(const float4*)&lB[kk][tx * 4];
      acc[0][0] += av.x * bv.x; acc[0][1] += av.x * bv.y; acc[0][2] += av.x * bv.z; acc[0][3] += av.x * bv.w;
      acc[1][0] += av.y * bv.x; acc[1][1] += av.y * bv.y; acc[1][2] += av.y * bv.z; acc[1][3] += av.y * bv.w;
      acc[2][0] += av.z * bv.x; acc[2][1] += av.z * bv.y; acc[2][2] += av.z * bv.z; acc[2][3] += av.z * bv.w;
      acc[3][0] += av.w * bv.x; acc[3][1] += av.w * bv.y; acc[3][2] += av.w * bv.z; acc[3][3] += av.w * bv.w;
    }
  }
  float colp2[4];
#pragma unroll
  for (int j = 0; j < 4; ++j)
    colp2[j] = o[(size_t)(Nbase + tx * 4 + j) * OLD + 2048];
#pragma unroll
  for (int i = 0; i < 4; ++i) {
    const int rg = Mbase + ty * 4 + i;
    float bv = 3.0e38f; int bj = 0;
#pragma unroll
    for (int j = 0; j < 4; ++j) {
      const int cg = Nbase + tx * 4 + j;
      const float d = colp2[j] - 2.0f * acc[i][j];
      if (cg != rg && d < bv) { bv = d; bj = cg; }
    }
#pragma unroll
    for (int m = 1; m < 16; m <<= 1) {
      const float ov = __shfl_xor(bv, m, 64);
      const int oj = __shfl_xor(bj, m, 64);
      if (ov < bv || (ov == bv && oj < bj)) { bv = ov; bj = oj; }
    }
    if (tx == 0)
      ((float2*)&o[(size_t)rg * OLD + 2056])[blockIdx.x] =
          make_float2(bv, __int_as_float(bj));
  }
}

__global__ __launch_bounds__(256) void argmin_final_f2(float* __restrict__ o, int nblk) {
  const int i = blockIdx.x, t = threadIdx.x;
  __shared__ int sj;
  if (t < 64) {
    float v = 3.4e38f; int j = 0x7fffffff;
    if (t < nblk) {
      const float2 p = ((const float2*)&o[(size_t)i * OLD + 2056])[t];
      v = p.x; j = __float_as_int(p.y);
    }
#pragma unroll
    for (int m = 32; m; m >>= 1) {
      const float ov = __shfl_xor(v, m, 64);
      const int oj = __shfl_xor(j, m, 64);
      if (ov < v || (ov == v && oj < j)) { v = ov; j = oj; }
    }
    if (t == 0) sj = (j < 0) ? 0 : (j > B - 1 ? B - 1 : j);
  }
  __syncthreads();
  const int j = sj;
  ((float4*)&o[(size_t)i * OLD + 2048])[t] = ((const float4*)&o[(size_t)j * OLD + D])[t];
}

extern "C" void kernel_launch(void* const* d_in, const int* in_sizes, int n_in,
                              void* d_out, int out_size, void* d_ws, size_t ws_size,
                              hipStream_t stream) {
  const float* anchor_x = (const float*)d_in[0];  // [4096,1024] f32
  const float* pos_x    = (const float*)d_in[1];  // [4096,1024] f32
  const float* W        = (const float*)d_in[2];  // [1024,1024] f32
  const float* b        = (const float*)d_in[3];  // [1024] f32
  float* out = (float*)d_out;                     // [4096,3072] f32
  char* ws = (char*)d_ws;
  const size_t MB = 1024 * 1024;

  if (ws_size >= 52 * MB) {  // uses exactly 52 MB (threshold proven rounds 5-7)
    u16* Aq     = (u16*)(ws);            // [4096][2048] bf16 hi|mid, 16 MB
    u16* Pq     = (u16*)(ws + 16 * MB);  // 16 MB
    u16* WtQ    = (u16*)(ws + 32 * MB);  // [1024][2048] bf16 hi|mid, 4 MB
    u16* posXq  = (u16*)(ws + 36 * MB);  // [4096][2048] bf16 hi|mid, 16 MB
    splitT_W<<<dim3(32, 32), dim3(32, 8), 0, stream>>>(W, WtQ);
    splitX2<<<2 * B, 256, 0, stream>>>(anchor_x, pos_x, (u16*)out, posXq);
    enc_mfma<<<dim3(8, 64), 256, 0, stream>>>(out, posXq, WtQ, b, Aq, Pq);
    pnorm<<<B, 256, 0, stream>>>(out);
    dist_mfma<<<dim3(32, 32), 256, 0, stream>>>(Aq, Pq, out);
    argmin_refine<<<B, 256, 0, stream>>>(out);
  } else {  // round-4 proven path: d_ws untouched
    enc_gemm<<<dim3(16, 64), 256, 0, stream>>>(anchor_x, W, b, out, 0);
    enc_gemm<<<dim3(16, 64), 256, 0, stream>>>(pos_x,    W, b, out, 1024);
    pnorm<<<B, 256, 0, stream>>>(out);
    dist_argmin_f32<<<dim3(64, 64), 256, 0, stream>>>(out);
    argmin_final_f2<<<B, 256, 0, stream>>>(out, 64);
  }
}